// Round 1
// baseline (2163.892 us; speedup 1.0000x reference)
//
#include <hip/hip_runtime.h>
#include <hip/hip_bf16.h>
#include <math.h>

#define NB 2
#define SEQ 1024
#define DM 768
#define NHEAD 12
#define HDIM 64
#define NEXP 8
#define FF 3072
#define NTOK (NB*SEQ)          // 2048
#define TDIM (3*DM)            // 2304
#define LNEPS 1e-5f

#define BM 64
#define BN 64
#define BK 16
#define LP 68                  // padded LDS row (16B-aligned, odd-bank-ish stride)

static __device__ __forceinline__ float bf2f(unsigned short u){
    return __uint_as_float(((unsigned)u) << 16);
}
static __device__ __forceinline__ unsigned short f2bf(float f){
    unsigned u = __float_as_uint(f);
    u += 0x7fffu + ((u >> 16) & 1u);   // RNE
    return (unsigned short)(u >> 16);
}
static __device__ __forceinline__ float gelu_exact(float x){
    return 0.5f * x * (1.0f + erff(x * 0.70710678118654752440f));
}

// ---------------- LayerNorm: one block (256 thr) per row of 768 ----------------
__global__ __launch_bounds__(256) void ln_kernel(const float* __restrict__ in,
                                                 const float* __restrict__ g,
                                                 const float* __restrict__ b,
                                                 float* __restrict__ out){
    int t = blockIdx.x;
    const float* row = in + (size_t)t * DM;
    int tid = threadIdx.x;
    float v0 = row[tid], v1 = row[tid + 256], v2 = row[tid + 512];
    float s  = v0 + v1 + v2;
    float ss = v0*v0 + v1*v1 + v2*v2;
    for (int off = 32; off; off >>= 1){
        s  += __shfl_down(s, off);
        ss += __shfl_down(ss, off);
    }
    __shared__ float ls[4], lss[4];
    int wid = tid >> 6, lane = tid & 63;
    if (lane == 0){ ls[wid] = s; lss[wid] = ss; }
    __syncthreads();
    if (tid == 0){
        float a = ls[0] + ls[1] + ls[2] + ls[3];
        float c = lss[0] + lss[1] + lss[2] + lss[3];
        float mu = a / (float)DM;
        float var = c / (float)DM - mu * mu;
        ls[0] = mu; lss[0] = rsqrtf(var + LNEPS);
    }
    __syncthreads();
    float mu = ls[0], rs = lss[0];
    float* orow = out + (size_t)t * DM;
    orow[tid]       = (v0 - mu) * rs * g[tid]       + b[tid];
    orow[tid + 256] = (v1 - mu) * rs * g[tid + 256] + b[tid + 256];
    orow[tid + 512] = (v2 - mu) * rs * g[tid + 512] + b[tid + 512];
}

// ---------------- QKV GEMM: [2048,768] @ [768,2304] + bias ----------------
__global__ __launch_bounds__(256) void gemm_qkv(const float* __restrict__ A,
                                                const float* __restrict__ Bm,
                                                const float* __restrict__ bias,
                                                float* __restrict__ C){
    __shared__ float As[BK][LP];
    __shared__ float Bs[BK][LP];
    int bm = blockIdx.y * BM, bn = blockIdx.x * BN;
    int tid = threadIdx.x;
    int tx = tid & 15, ty = tid >> 4;
    int arow = tid >> 2, akk = (tid & 3) * 4;
    int bkk = tid >> 4, bn0 = (tid & 15) * 4;
    float acc[4][4] = {};
    for (int kb = 0; kb < DM; kb += BK){
        float4 av = *(const float4*)&A[(size_t)(bm + arow) * DM + kb + akk];
        float4 bv = *(const float4*)&Bm[(size_t)(kb + bkk) * TDIM + bn + bn0];
        As[akk+0][arow] = av.x; As[akk+1][arow] = av.y;
        As[akk+2][arow] = av.z; As[akk+3][arow] = av.w;
        *(float4*)&Bs[bkk][bn0] = bv;
        __syncthreads();
        #pragma unroll
        for (int kk = 0; kk < BK; kk++){
            float4 a = *(const float4*)&As[kk][ty*4];
            float4 b = *(const float4*)&Bs[kk][tx*4];
            acc[0][0] += a.x*b.x; acc[0][1] += a.x*b.y; acc[0][2] += a.x*b.z; acc[0][3] += a.x*b.w;
            acc[1][0] += a.y*b.x; acc[1][1] += a.y*b.y; acc[1][2] += a.y*b.z; acc[1][3] += a.y*b.w;
            acc[2][0] += a.z*b.x; acc[2][1] += a.z*b.y; acc[2][2] += a.z*b.z; acc[2][3] += a.z*b.w;
            acc[3][0] += a.w*b.x; acc[3][1] += a.w*b.y; acc[3][2] += a.w*b.z; acc[3][3] += a.w*b.w;
        }
        __syncthreads();
    }
    float4 bb = *(const float4*)&bias[bn + tx*4];
    #pragma unroll
    for (int i = 0; i < 4; i++){
        int row = bm + ty*4 + i;
        float4 o;
        o.x = acc[i][0] + bb.x; o.y = acc[i][1] + bb.y;
        o.z = acc[i][2] + bb.z; o.w = acc[i][3] + bb.w;
        *(float4*)&C[(size_t)row * TDIM + bn + tx*4] = o;
    }
}

// ---------------- Attention: one wave per (b,h,q) row, lanes over head dim ----------------
__global__ __launch_bounds__(64) void attn_kernel(const float* __restrict__ qkv,
                                                  float* __restrict__ ctx){
    int r = blockIdx.x;
    int q = r & (SEQ - 1);
    int bh = r >> 10;
    int h = bh % NHEAD, b = bh / NHEAD;
    int lane = threadIdx.x;
    const float* qrow = qkv + (size_t)(b*SEQ + q) * TDIM + h*HDIM;
    float qv = qrow[lane] * 0.125f;   // fold 1/sqrt(64)
    const float* kbase = qkv + (size_t)b*SEQ*TDIM + DM       + h*HDIM;
    const float* vbase = qkv + (size_t)b*SEQ*TDIM + 2*DM     + h*HDIM;
    float m = -INFINITY, l = 0.f, acc = 0.f;
    for (int k = 0; k <= q; k++){
        float s = qv * kbase[(size_t)k*TDIM + lane];
        #pragma unroll
        for (int off = 32; off; off >>= 1) s += __shfl_xor(s, off);
        float vval = vbase[(size_t)k*TDIM + lane];
        float mn = fmaxf(m, s);
        float f = __expf(m - mn);
        float p = __expf(s - mn);
        l = l * f + p;
        acc = acc * f + p * vval;
        m = mn;
    }
    ctx[(size_t)(b*SEQ + q) * DM + h*HDIM + lane] = acc / l;
}

// ---------------- Attn-proj GEMM + residual: [2048,768]@[768,768]+bias+res ----------------
__global__ __launch_bounds__(256) void gemm_attnproj(const float* __restrict__ A,
                                                     const float* __restrict__ Bm,
                                                     const float* __restrict__ bias,
                                                     const float* __restrict__ res,
                                                     float* __restrict__ C){
    __shared__ float As[BK][LP];
    __shared__ float Bs[BK][LP];
    int bm = blockIdx.y * BM, bn = blockIdx.x * BN;
    int tid = threadIdx.x;
    int tx = tid & 15, ty = tid >> 4;
    int arow = tid >> 2, akk = (tid & 3) * 4;
    int bkk = tid >> 4, bn0 = (tid & 15) * 4;
    float acc[4][4] = {};
    for (int kb = 0; kb < DM; kb += BK){
        float4 av = *(const float4*)&A[(size_t)(bm + arow) * DM + kb + akk];
        float4 bv = *(const float4*)&Bm[(size_t)(kb + bkk) * DM + bn + bn0];
        As[akk+0][arow] = av.x; As[akk+1][arow] = av.y;
        As[akk+2][arow] = av.z; As[akk+3][arow] = av.w;
        *(float4*)&Bs[bkk][bn0] = bv;
        __syncthreads();
        #pragma unroll
        for (int kk = 0; kk < BK; kk++){
            float4 a = *(const float4*)&As[kk][ty*4];
            float4 b = *(const float4*)&Bs[kk][tx*4];
            acc[0][0] += a.x*b.x; acc[0][1] += a.x*b.y; acc[0][2] += a.x*b.z; acc[0][3] += a.x*b.w;
            acc[1][0] += a.y*b.x; acc[1][1] += a.y*b.y; acc[1][2] += a.y*b.z; acc[1][3] += a.y*b.w;
            acc[2][0] += a.z*b.x; acc[2][1] += a.z*b.y; acc[2][2] += a.z*b.z; acc[2][3] += a.z*b.w;
            acc[3][0] += a.w*b.x; acc[3][1] += a.w*b.y; acc[3][2] += a.w*b.z; acc[3][3] += a.w*b.w;
        }
        __syncthreads();
    }
    float4 bb = *(const float4*)&bias[bn + tx*4];
    #pragma unroll
    for (int i = 0; i < 4; i++){
        int row = bm + ty*4 + i;
        float4 rr = *(const float4*)&res[(size_t)row * DM + bn + tx*4];
        float4 o;
        o.x = acc[i][0] + bb.x + rr.x; o.y = acc[i][1] + bb.y + rr.y;
        o.z = acc[i][2] + bb.z + rr.z; o.w = acc[i][3] + bb.w + rr.w;
        *(float4*)&C[(size_t)row * DM + bn + tx*4] = o;
    }
}

// ---------------- Router: one wave per token ----------------
__global__ __launch_bounds__(64) void router_kernel(const float* __restrict__ x2,
                                                    const float* __restrict__ wr,
                                                    int* __restrict__ cnt,
                                                    int* __restrict__ expTok,
                                                    int* __restrict__ tokE,
                                                    int* __restrict__ tokPos,
                                                    float* __restrict__ tokGate){
    int t = blockIdx.x;
    int lane = threadIdx.x;
    const float* xr = x2 + (size_t)t * DM;
    float acc[NEXP] = {};
    for (int d = lane; d < DM; d += 64){
        float xv = xr[d];
        #pragma unroll
        for (int e = 0; e < NEXP; e++) acc[e] += xv * wr[e*DM + d];
    }
    #pragma unroll
    for (int e = 0; e < NEXP; e++)
        for (int off = 32; off; off >>= 1) acc[e] += __shfl_xor(acc[e], off);
    if (lane == 0){
        int i0 = 0; float m0 = acc[0];
        #pragma unroll
        for (int e = 1; e < NEXP; e++) if (acc[e] > m0){ m0 = acc[e]; i0 = e; }
        int i1 = -1; float m1 = -INFINITY;
        #pragma unroll
        for (int e = 0; e < NEXP; e++) if (e != i0 && acc[e] > m1){ m1 = acc[e]; i1 = e; }
        float mx = fmaxf(m0, m1);
        float e0 = __expf(m0 - mx), e1 = __expf(m1 - mx);
        float inv = 1.0f / (e0 + e1);
        int p0 = atomicAdd(&cnt[i0], 1);
        int p1 = atomicAdd(&cnt[i1], 1);
        expTok[i0*NTOK + p0] = t;
        expTok[i1*NTOK + p1] = t;
        tokE[t*2]   = i0; tokE[t*2+1]   = i1;
        tokPos[t*2] = p0; tokPos[t*2+1] = p1;
        tokGate[t*2]   = e0 * inv;
        tokGate[t*2+1] = e1 * inv;
    }
}

__global__ void offsets_kernel(const int* __restrict__ cnt, int* __restrict__ offE){
    if (threadIdx.x == 0 && blockIdx.x == 0){
        int a = 0;
        for (int e = 0; e < NEXP; e++){ offE[e] = a; a += cnt[e]; }
    }
}

// ---------------- MoE fc: gathered [rows,768] @ w_fc[e] (768x3072) + b, gelu, bf16 out ----------------
__global__ __launch_bounds__(256) void gemm_fc(const float* __restrict__ X,
                                               const float* __restrict__ Wfc,
                                               const float* __restrict__ bfc,
                                               const int* __restrict__ expTok,
                                               const int* __restrict__ cnt,
                                               const int* __restrict__ offE,
                                               unsigned short* __restrict__ H){
    int e = blockIdx.z, tile = blockIdx.y;
    int c = cnt[e];
    int rows = c - tile * BM;
    if (rows <= 0) return;
    __shared__ float As[BK][LP];
    __shared__ float Bs[BK][LP];
    __shared__ int toks[BM];
    int bn = blockIdx.x * BN;
    int tid = threadIdx.x;
    if (tid < BM){
        int idx = tile * BM + tid;
        if (idx >= c) idx = c - 1;
        toks[tid] = expTok[e*NTOK + idx];
    }
    __syncthreads();
    int tx = tid & 15, ty = tid >> 4;
    int arow = tid >> 2, akk = (tid & 3) * 4;
    int bkk = tid >> 4, bn0 = (tid & 15) * 4;
    const float* Bm = Wfc + (size_t)e * DM * FF;
    int tokA = toks[arow];
    float acc[4][4] = {};
    for (int kb = 0; kb < DM; kb += BK){
        float4 av = *(const float4*)&X[(size_t)tokA * DM + kb + akk];
        float4 bv = *(const float4*)&Bm[(size_t)(kb + bkk) * FF + bn + bn0];
        As[akk+0][arow] = av.x; As[akk+1][arow] = av.y;
        As[akk+2][arow] = av.z; As[akk+3][arow] = av.w;
        *(float4*)&Bs[bkk][bn0] = bv;
        __syncthreads();
        #pragma unroll
        for (int kk = 0; kk < BK; kk++){
            float4 a = *(const float4*)&As[kk][ty*4];
            float4 b = *(const float4*)&Bs[kk][tx*4];
            acc[0][0] += a.x*b.x; acc[0][1] += a.x*b.y; acc[0][2] += a.x*b.z; acc[0][3] += a.x*b.w;
            acc[1][0] += a.y*b.x; acc[1][1] += a.y*b.y; acc[1][2] += a.y*b.z; acc[1][3] += a.y*b.w;
            acc[2][0] += a.z*b.x; acc[2][1] += a.z*b.y; acc[2][2] += a.z*b.z; acc[2][3] += a.z*b.w;
            acc[3][0] += a.w*b.x; acc[3][1] += a.w*b.y; acc[3][2] += a.w*b.z; acc[3][3] += a.w*b.w;
        }
        __syncthreads();
    }
    int slot0 = offE[e] + tile * BM;
    float4 bb = *(const float4*)&bfc[(size_t)e*FF + bn + tx*4];
    #pragma unroll
    for (int i = 0; i < 4; i++){
        int mloc = ty*4 + i;
        if (mloc < rows){
            ushort4 o;
            o.x = f2bf(gelu_exact(acc[i][0] + bb.x));
            o.y = f2bf(gelu_exact(acc[i][1] + bb.y));
            o.z = f2bf(gelu_exact(acc[i][2] + bb.z));
            o.w = f2bf(gelu_exact(acc[i][3] + bb.w));
            *(ushort4*)&H[(size_t)(slot0 + mloc) * FF + bn + tx*4] = o;
        }
    }
}

// ---------------- MoE proj: [rows,3072](bf16) @ w_proj[e] (3072x768) -> y ----------------
__global__ __launch_bounds__(256) void gemm_proj(const unsigned short* __restrict__ H,
                                                 const float* __restrict__ Wpr,
                                                 const int* __restrict__ cnt,
                                                 const int* __restrict__ offE,
                                                 float* __restrict__ Y){
    int e = blockIdx.z, tile = blockIdx.y;
    int c = cnt[e];
    int rows = c - tile * BM;
    if (rows <= 0) return;
    __shared__ float As[BK][LP];
    __shared__ float Bs[BK][LP];
    int bn = blockIdx.x * BN;
    int tid = threadIdx.x;
    int tx = tid & 15, ty = tid >> 4;
    int arow = tid >> 2, akk = (tid & 3) * 4;
    int bkk = tid >> 4, bn0 = (tid & 15) * 4;
    int slot0 = offE[e] + tile * BM;
    int ar = arow < rows ? arow : rows - 1;   // clamp to avoid OOB reads past h
    const unsigned short* Arow = H + (size_t)(slot0 + ar) * FF;
    const float* Bm = Wpr + (size_t)e * FF * DM;
    float acc[4][4] = {};
    for (int kb = 0; kb < FF; kb += BK){
        ushort4 rv = *(const ushort4*)&Arow[kb + akk];
        float4 bv = *(const float4*)&Bm[(size_t)(kb + bkk) * DM + bn + bn0];
        As[akk+0][arow] = bf2f(rv.x); As[akk+1][arow] = bf2f(rv.y);
        As[akk+2][arow] = bf2f(rv.z); As[akk+3][arow] = bf2f(rv.w);
        *(float4*)&Bs[bkk][bn0] = bv;
        __syncthreads();
        #pragma unroll
        for (int kk = 0; kk < BK; kk++){
            float4 a = *(const float4*)&As[kk][ty*4];
            float4 b = *(const float4*)&Bs[kk][tx*4];
            acc[0][0] += a.x*b.x; acc[0][1] += a.x*b.y; acc[0][2] += a.x*b.z; acc[0][3] += a.x*b.w;
            acc[1][0] += a.y*b.x; acc[1][1] += a.y*b.y; acc[1][2] += a.y*b.z; acc[1][3] += a.y*b.w;
            acc[2][0] += a.z*b.x; acc[2][1] += a.z*b.y; acc[2][2] += a.z*b.z; acc[2][3] += a.z*b.w;
            acc[3][0] += a.w*b.x; acc[3][1] += a.w*b.y; acc[3][2] += a.w*b.z; acc[3][3] += a.w*b.w;
        }
        __syncthreads();
    }
    #pragma unroll
    for (int i = 0; i < 4; i++){
        int mloc = ty*4 + i;
        if (mloc < rows){
            float4 o;
            o.x = acc[i][0]; o.y = acc[i][1]; o.z = acc[i][2]; o.w = acc[i][3];
            *(float4*)&Y[(size_t)(slot0 + mloc) * DM + bn + tx*4] = o;
        }
    }
}

// ---------------- Combine: out = hs + sum_k gate_k * (y_k + b_proj[e_k]) ----------------
__global__ __launch_bounds__(256) void combine_kernel(const float* __restrict__ hs,
                                                      const float* __restrict__ Y,
                                                      const float* __restrict__ bproj,
                                                      const int* __restrict__ tokE,
                                                      const int* __restrict__ tokPos,
                                                      const float* __restrict__ tokGate,
                                                      const int* __restrict__ offE,
                                                      float* __restrict__ out){
    int t = blockIdx.x;
    int e0 = tokE[t*2], e1 = tokE[t*2+1];
    int s0 = offE[e0] + tokPos[t*2];
    int s1 = offE[e1] + tokPos[t*2+1];
    float g0 = tokGate[t*2], g1 = tokGate[t*2+1];
    const float* y0 = Y + (size_t)s0 * DM;
    const float* y1 = Y + (size_t)s1 * DM;
    const float* b0 = bproj + (size_t)e0 * DM;
    const float* b1 = bproj + (size_t)e1 * DM;
    const float* hr = hs + (size_t)t * DM;
    float* orow = out + (size_t)t * DM;
    for (int d = threadIdx.x; d < DM; d += 256){
        orow[d] = hr[d] + g0 * (y0[d] + b0[d]) + g1 * (y1[d] + b1[d]);
    }
}

extern "C" void kernel_launch(void* const* d_in, const int* in_sizes, int n_in,
                              void* d_out, int out_size, void* d_ws, size_t ws_size,
                              hipStream_t stream){
    (void)in_sizes; (void)n_in; (void)out_size; (void)ws_size;
    const float* hidden  = (const float*)d_in[0];
    const float* ln1_g   = (const float*)d_in[1];
    const float* ln1_b   = (const float*)d_in[2];
    const float* w_attn  = (const float*)d_in[3];
    const float* b_attn  = (const float*)d_in[4];
    const float* w_aproj = (const float*)d_in[5];
    const float* b_aproj = (const float*)d_in[6];
    const float* ln2_g   = (const float*)d_in[7];
    const float* ln2_b   = (const float*)d_in[8];
    const float* w_rout  = (const float*)d_in[9];
    const float* w_fc    = (const float*)d_in[10];
    const float* b_fc    = (const float*)d_in[11];
    const float* w_proj  = (const float*)d_in[12];
    const float* b_proj  = (const float*)d_in[13];
    float* out = (float*)d_out;

    char* ws = (char*)d_ws;
    float* x    = (float*)(ws + 0);                     //  6291456 B
    float* hs   = (float*)(ws + 6291456);               //  6291456 B
    float* y    = (float*)(ws + 12582912);              // 12582912 B
    float* qkv  = (float*)(ws + 25165824);              // 18874368 B
    float* ctx  = (float*)(ws + 44040192);              //  6291456 B
    unsigned short* hbuf = (unsigned short*)(ws + 25165824); // reuses qkv+ctx (25165824 B)
    char* rt = ws + 50331648;
    int* cnt      = (int*)(rt + 0);
    int* offE     = (int*)(rt + 32);
    int* expTok   = (int*)(rt + 64);                    // 8*2048*4 = 65536
    int* tokE     = (int*)(rt + 64 + 65536);            // 4096*4
    int* tokPos   = (int*)(rt + 64 + 65536 + 16384);    // 4096*4
    float* tokGate= (float*)(rt + 64 + 65536 + 32768);  // 4096*4

    hipMemsetAsync(cnt, 0, NEXP * sizeof(int), stream);

    ln_kernel<<<NTOK, 256, 0, stream>>>(hidden, ln1_g, ln1_b, x);
    gemm_qkv<<<dim3(TDIM/BN, NTOK/BM), 256, 0, stream>>>(x, w_attn, b_attn, qkv);
    attn_kernel<<<NB*NHEAD*SEQ, 64, 0, stream>>>(qkv, ctx);
    gemm_attnproj<<<dim3(DM/BN, NTOK/BM), 256, 0, stream>>>(ctx, w_aproj, b_aproj, hidden, hs);
    ln_kernel<<<NTOK, 256, 0, stream>>>(hs, ln2_g, ln2_b, x);
    router_kernel<<<NTOK, 64, 0, stream>>>(x, w_rout, cnt, expTok, tokE, tokPos, tokGate);
    offsets_kernel<<<1, 64, 0, stream>>>(cnt, offE);
    gemm_fc<<<dim3(FF/BN, NTOK/BM, NEXP), 256, 0, stream>>>(x, w_fc, b_fc, expTok, cnt, offE, hbuf);
    gemm_proj<<<dim3(DM/BN, NTOK/BM, NEXP), 256, 0, stream>>>(hbuf, w_proj, cnt, offE, y);
    combine_kernel<<<NTOK, 256, 0, stream>>>(hs, y, b_proj, tokE, tokPos, tokGate, offE, out);
}

// Round 3
// 1149.189 us; speedup vs baseline: 1.8830x; 1.8830x over previous
//
#include <hip/hip_runtime.h>
#include <hip/hip_bf16.h>
#include <math.h>

#define NB 2
#define SEQ 1024
#define DM 768
#define NHEAD 12
#define HDIM 64
#define NEXP 8
#define FF 3072
#define NTOK (NB*SEQ)          // 2048
#define TDIM (3*DM)            // 2304
#define LNEPS 1e-5f

#define BM 64
#define BN 64
#define BK 16
#define LP 68                  // padded LDS row

typedef __attribute__((ext_vector_type(8))) short v8s;
typedef __attribute__((ext_vector_type(4))) float v4f;

static __device__ __forceinline__ float bf2f(unsigned short u){
    return __uint_as_float(((unsigned)u) << 16);
}
static __device__ __forceinline__ unsigned short f2bf(float f){
    unsigned u = __float_as_uint(f);
    u += 0x7fffu + ((u >> 16) & 1u);   // RNE
    return (unsigned short)(u >> 16);
}
static __device__ __forceinline__ float gelu_exact(float x){
    return 0.5f * x * (1.0f + erff(x * 0.70710678118654752440f));
}

// ---------------- LayerNorm: one block (256 thr) per row of 768 ----------------
__global__ __launch_bounds__(256) void ln_kernel(const float* __restrict__ in,
                                                 const float* __restrict__ g,
                                                 const float* __restrict__ b,
                                                 float* __restrict__ out){
    int t = blockIdx.x;
    const float* row = in + (size_t)t * DM;
    int tid = threadIdx.x;
    float v0 = row[tid], v1 = row[tid + 256], v2 = row[tid + 512];
    float s  = v0 + v1 + v2;
    float ss = v0*v0 + v1*v1 + v2*v2;
    for (int off = 32; off; off >>= 1){
        s  += __shfl_down(s, off);
        ss += __shfl_down(ss, off);
    }
    __shared__ float ls[4], lss[4];
    int wid = tid >> 6, lane = tid & 63;
    if (lane == 0){ ls[wid] = s; lss[wid] = ss; }
    __syncthreads();
    if (tid == 0){
        float a = ls[0] + ls[1] + ls[2] + ls[3];
        float c = lss[0] + lss[1] + lss[2] + lss[3];
        float mu = a / (float)DM;
        float var = c / (float)DM - mu * mu;
        ls[0] = mu; lss[0] = rsqrtf(var + LNEPS);
    }
    __syncthreads();
    float mu = ls[0], rs = lss[0];
    float* orow = out + (size_t)t * DM;
    orow[tid]       = (v0 - mu) * rs * g[tid]       + b[tid];
    orow[tid + 256] = (v1 - mu) * rs * g[tid + 256] + b[tid + 256];
    orow[tid + 512] = (v2 - mu) * rs * g[tid + 512] + b[tid + 512];
}

// ---------------- QKV GEMM: [2048,768] @ [768,2304] + bias ----------------
__global__ __launch_bounds__(256) void gemm_qkv(const float* __restrict__ A,
                                                const float* __restrict__ Bm,
                                                const float* __restrict__ bias,
                                                float* __restrict__ C){
    __shared__ float As[BK][LP];
    __shared__ float Bs[BK][LP];
    int bm = blockIdx.y * BM, bn = blockIdx.x * BN;
    int tid = threadIdx.x;
    int tx = tid & 15, ty = tid >> 4;
    int arow = tid >> 2, akk = (tid & 3) * 4;
    int bkk = tid >> 4, bn0 = (tid & 15) * 4;
    float acc[4][4] = {};
    for (int kb = 0; kb < DM; kb += BK){
        float4 av = *(const float4*)&A[(size_t)(bm + arow) * DM + kb + akk];
        float4 bv = *(const float4*)&Bm[(size_t)(kb + bkk) * TDIM + bn + bn0];
        As[akk+0][arow] = av.x; As[akk+1][arow] = av.y;
        As[akk+2][arow] = av.z; As[akk+3][arow] = av.w;
        *(float4*)&Bs[bkk][bn0] = bv;
        __syncthreads();
        #pragma unroll
        for (int kk = 0; kk < BK; kk++){
            float4 a = *(const float4*)&As[kk][ty*4];
            float4 b = *(const float4*)&Bs[kk][tx*4];
            acc[0][0] += a.x*b.x; acc[0][1] += a.x*b.y; acc[0][2] += a.x*b.z; acc[0][3] += a.x*b.w;
            acc[1][0] += a.y*b.x; acc[1][1] += a.y*b.y; acc[1][2] += a.y*b.z; acc[1][3] += a.y*b.w;
            acc[2][0] += a.z*b.x; acc[2][1] += a.z*b.y; acc[2][2] += a.z*b.z; acc[2][3] += a.z*b.w;
            acc[3][0] += a.w*b.x; acc[3][1] += a.w*b.y; acc[3][2] += a.w*b.z; acc[3][3] += a.w*b.w;
        }
        __syncthreads();
    }
    float4 bb = *(const float4*)&bias[bn + tx*4];
    #pragma unroll
    for (int i = 0; i < 4; i++){
        int row = bm + ty*4 + i;
        float4 o;
        o.x = acc[i][0] + bb.x; o.y = acc[i][1] + bb.y;
        o.z = acc[i][2] + bb.z; o.w = acc[i][3] + bb.w;
        *(float4*)&C[(size_t)row * TDIM + bn + tx*4] = o;
    }
}

// ---------------- Attention prep: qkv f32 -> Qb/Kb bf16 [bh][s][64], Vt bf16 [bh][d][s] ----------------
__global__ __launch_bounds__(256) void attn_prep(const float* __restrict__ qkv,
                                                 unsigned short* __restrict__ Qb,
                                                 unsigned short* __restrict__ Kb,
                                                 unsigned short* __restrict__ Vt){
    int bi = blockIdx.x;                 // bh*16 + chunk
    int c = bi & 15, bh = bi >> 4;
    int h = bh % NHEAD, b = bh / NHEAD;
    __shared__ float vt[64][65];
    int tid = threadIdx.x;
    int row = tid >> 2, ds = (tid & 3) * 16;
    const float* base = qkv + (size_t)(b*SEQ + c*64 + row) * TDIM + h*HDIM + ds;
    size_t qkrow = ((size_t)bh*SEQ + c*64 + row) * HDIM + ds;
    #pragma unroll
    for (int j = 0; j < 16; j += 4){
        float4 qv = *(const float4*)(base + j);
        ushort4 qo;
        qo.x = f2bf(qv.x*0.125f); qo.y = f2bf(qv.y*0.125f);
        qo.z = f2bf(qv.z*0.125f); qo.w = f2bf(qv.w*0.125f);
        *(ushort4*)&Qb[qkrow + j] = qo;
        float4 kv = *(const float4*)(base + DM + j);
        ushort4 ko;
        ko.x = f2bf(kv.x); ko.y = f2bf(kv.y); ko.z = f2bf(kv.z); ko.w = f2bf(kv.w);
        *(ushort4*)&Kb[qkrow + j] = ko;
        float4 vv = *(const float4*)(base + 2*DM + j);
        vt[row][ds+j+0] = vv.x; vt[row][ds+j+1] = vv.y;
        vt[row][ds+j+2] = vv.z; vt[row][ds+j+3] = vv.w;
    }
    __syncthreads();
    int d = tid >> 2, ks = (tid & 3) * 16;
    size_t vrow = ((size_t)bh*HDIM + d) * SEQ + c*64 + ks;
    #pragma unroll
    for (int j = 0; j < 16; j += 4){
        ushort4 o;
        o.x = f2bf(vt[ks+j+0][d]); o.y = f2bf(vt[ks+j+1][d]);
        o.z = f2bf(vt[ks+j+2][d]); o.w = f2bf(vt[ks+j+3][d]);
        *(ushort4*)&Vt[vrow + j] = o;
    }
}

// ---------------- Flash attention: one wave per (bh, 16-query tile) ----------------
__global__ __launch_bounds__(64) void fattn(const unsigned short* __restrict__ Qb,
                                            const unsigned short* __restrict__ Kb,
                                            const unsigned short* __restrict__ Vt,
                                            float* __restrict__ ctx){
    int bh = blockIdx.x >> 6;
    int q0 = (63 - (blockIdx.x & 63)) * 16;   // long tiles dispatched first
    int h = bh % NHEAD, b = bh / NHEAD;
    int lane = threadIdx.x;
    int quad = lane >> 4, l15 = lane & 15;

    __shared__ __align__(16) unsigned short Plds[16*32];

    const unsigned short* qp = Qb + ((size_t)bh*SEQ + q0 + l15) * HDIM + quad*8;
    v8s qa0 = *(const v8s*)qp;
    v8s qa1 = *(const v8s*)(qp + 32);

    v4f o0 = {0,0,0,0}, o1 = {0,0,0,0}, o2 = {0,0,0,0}, o3 = {0,0,0,0};
    float mrow[4] = {-1e30f,-1e30f,-1e30f,-1e30f};
    float lrow[4] = {0,0,0,0};

    int nch = (q0 + 16 + 31) >> 5;
    for (int ch = 0; ch < nch; ch++){
        int kt = ch * 32;
        const unsigned short* kp = Kb + ((size_t)bh*SEQ + kt + l15) * HDIM + quad*8;
        v8s kb0l = *(const v8s*)kp;
        v8s kb0h = *(const v8s*)(kp + 32);
        v8s kb1l = *(const v8s*)(kp + 16*HDIM);
        v8s kb1h = *(const v8s*)(kp + 16*HDIM + 32);
        v4f s0 = {0,0,0,0}, s1 = {0,0,0,0};
        s0 = __builtin_amdgcn_mfma_f32_16x16x32_bf16(qa0, kb0l, s0, 0, 0, 0);
        s0 = __builtin_amdgcn_mfma_f32_16x16x32_bf16(qa1, kb0h, s0, 0, 0, 0);
        s1 = __builtin_amdgcn_mfma_f32_16x16x32_bf16(qa0, kb1l, s1, 0, 0, 0);
        s1 = __builtin_amdgcn_mfma_f32_16x16x32_bf16(qa1, kb1h, s1, 0, 0, 0);

        int key0 = kt + l15, key1 = kt + 16 + l15;
        float alpha[4];
        #pragma unroll
        for (int r = 0; r < 4; r++){
            int qrow = q0 + quad*4 + r;
            float v0 = (key0 <= qrow) ? s0[r] : -1e30f;
            float v1 = (key1 <= qrow) ? s1[r] : -1e30f;
            float mx = fmaxf(v0, v1);
            mx = fmaxf(mx, __shfl_xor(mx, 1));
            mx = fmaxf(mx, __shfl_xor(mx, 2));
            mx = fmaxf(mx, __shfl_xor(mx, 4));
            mx = fmaxf(mx, __shfl_xor(mx, 8));
            float mn = fmaxf(mrow[r], mx);
            alpha[r] = __expf(mrow[r] - mn);
            float p0 = __expf(v0 - mn);
            float p1 = __expf(v1 - mn);
            float ps = p0 + p1;
            ps += __shfl_xor(ps, 1);
            ps += __shfl_xor(ps, 2);
            ps += __shfl_xor(ps, 4);
            ps += __shfl_xor(ps, 8);
            lrow[r] = lrow[r] * alpha[r] + ps;
            mrow[r] = mn;
            Plds[(quad*4 + r)*32 + l15]      = f2bf(p0);
            Plds[(quad*4 + r)*32 + 16 + l15] = f2bf(p1);
        }
        #pragma unroll
        for (int r = 0; r < 4; r++){
            o0[r] *= alpha[r]; o1[r] *= alpha[r];
            o2[r] *= alpha[r]; o3[r] *= alpha[r];
        }
        __syncthreads();
        v8s pa = *(const v8s*)&Plds[l15*32 + quad*8];
        const unsigned short* vp = Vt + ((size_t)bh*HDIM + l15) * SEQ + kt + quad*8;
        v8s vb0 = *(const v8s*)vp;
        v8s vb1 = *(const v8s*)(vp + 16*SEQ);
        v8s vb2 = *(const v8s*)(vp + 32*SEQ);
        v8s vb3 = *(const v8s*)(vp + 48*SEQ);
        o0 = __builtin_amdgcn_mfma_f32_16x16x32_bf16(pa, vb0, o0, 0, 0, 0);
        o1 = __builtin_amdgcn_mfma_f32_16x16x32_bf16(pa, vb1, o1, 0, 0, 0);
        o2 = __builtin_amdgcn_mfma_f32_16x16x32_bf16(pa, vb2, o2, 0, 0, 0);
        o3 = __builtin_amdgcn_mfma_f32_16x16x32_bf16(pa, vb3, o3, 0, 0, 0);
        __syncthreads();
    }
    // epilogue: divide by l, write ctx f32 [tok][768]
    #pragma unroll
    for (int r = 0; r < 4; r++){
        float inv = 1.0f / lrow[r];
        size_t orow = (size_t)(b*SEQ + q0 + quad*4 + r) * DM + h*HDIM;
        ctx[orow + l15]      = o0[r] * inv;
        ctx[orow + 16 + l15] = o1[r] * inv;
        ctx[orow + 32 + l15] = o2[r] * inv;
        ctx[orow + 48 + l15] = o3[r] * inv;
    }
}

// ---------------- Attn-proj GEMM + residual: [2048,768]@[768,768]+bias+res ----------------
__global__ __launch_bounds__(256) void gemm_attnproj(const float* __restrict__ A,
                                                     const float* __restrict__ Bm,
                                                     const float* __restrict__ bias,
                                                     const float* __restrict__ res,
                                                     float* __restrict__ C){
    __shared__ float As[BK][LP];
    __shared__ float Bs[BK][LP];
    int bm = blockIdx.y * BM, bn = blockIdx.x * BN;
    int tid = threadIdx.x;
    int tx = tid & 15, ty = tid >> 4;
    int arow = tid >> 2, akk = (tid & 3) * 4;
    int bkk = tid >> 4, bn0 = (tid & 15) * 4;
    float acc[4][4] = {};
    for (int kb = 0; kb < DM; kb += BK){
        float4 av = *(const float4*)&A[(size_t)(bm + arow) * DM + kb + akk];
        float4 bv = *(const float4*)&Bm[(size_t)(kb + bkk) * DM + bn + bn0];
        As[akk+0][arow] = av.x; As[akk+1][arow] = av.y;
        As[akk+2][arow] = av.z; As[akk+3][arow] = av.w;
        *(float4*)&Bs[bkk][bn0] = bv;
        __syncthreads();
        #pragma unroll
        for (int kk = 0; kk < BK; kk++){
            float4 a = *(const float4*)&As[kk][ty*4];
            float4 b = *(const float4*)&Bs[kk][tx*4];
            acc[0][0] += a.x*b.x; acc[0][1] += a.x*b.y; acc[0][2] += a.x*b.z; acc[0][3] += a.x*b.w;
            acc[1][0] += a.y*b.x; acc[1][1] += a.y*b.y; acc[1][2] += a.y*b.z; acc[1][3] += a.y*b.w;
            acc[2][0] += a.z*b.x; acc[2][1] += a.z*b.y; acc[2][2] += a.z*b.z; acc[2][3] += a.z*b.w;
            acc[3][0] += a.w*b.x; acc[3][1] += a.w*b.y; acc[3][2] += a.w*b.z; acc[3][3] += a.w*b.w;
        }
        __syncthreads();
    }
    float4 bb = *(const float4*)&bias[bn + tx*4];
    #pragma unroll
    for (int i = 0; i < 4; i++){
        int row = bm + ty*4 + i;
        float4 rr = *(const float4*)&res[(size_t)row * DM + bn + tx*4];
        float4 o;
        o.x = acc[i][0] + bb.x + rr.x; o.y = acc[i][1] + bb.y + rr.y;
        o.z = acc[i][2] + bb.z + rr.z; o.w = acc[i][3] + bb.w + rr.w;
        *(float4*)&C[(size_t)row * DM + bn + tx*4] = o;
    }
}

// ---------------- Router: one wave per token ----------------
__global__ __launch_bounds__(64) void router_kernel(const float* __restrict__ x2,
                                                    const float* __restrict__ wr,
                                                    int* __restrict__ cnt,
                                                    int* __restrict__ expTok,
                                                    int* __restrict__ tokE,
                                                    int* __restrict__ tokPos,
                                                    float* __restrict__ tokGate){
    int t = blockIdx.x;
    int lane = threadIdx.x;
    const float* xr = x2 + (size_t)t * DM;
    float acc[NEXP] = {};
    for (int d = lane; d < DM; d += 64){
        float xv = xr[d];
        #pragma unroll
        for (int e = 0; e < NEXP; e++) acc[e] += xv * wr[e*DM + d];
    }
    #pragma unroll
    for (int e = 0; e < NEXP; e++)
        for (int off = 32; off; off >>= 1) acc[e] += __shfl_xor(acc[e], off);
    if (lane == 0){
        int i0 = 0; float m0 = acc[0];
        #pragma unroll
        for (int e = 1; e < NEXP; e++) if (acc[e] > m0){ m0 = acc[e]; i0 = e; }
        int i1 = -1; float m1 = -INFINITY;
        #pragma unroll
        for (int e = 0; e < NEXP; e++) if (e != i0 && acc[e] > m1){ m1 = acc[e]; i1 = e; }
        float mx = fmaxf(m0, m1);
        float e0 = __expf(m0 - mx), e1 = __expf(m1 - mx);
        float inv = 1.0f / (e0 + e1);
        int p0 = atomicAdd(&cnt[i0], 1);
        int p1 = atomicAdd(&cnt[i1], 1);
        expTok[i0*NTOK + p0] = t;
        expTok[i1*NTOK + p1] = t;
        tokE[t*2]   = i0; tokE[t*2+1]   = i1;
        tokPos[t*2] = p0; tokPos[t*2+1] = p1;
        tokGate[t*2]   = e0 * inv;
        tokGate[t*2+1] = e1 * inv;
    }
}

__global__ void offsets_kernel(const int* __restrict__ cnt, int* __restrict__ offE){
    if (threadIdx.x == 0 && blockIdx.x == 0){
        int a = 0;
        for (int e = 0; e < NEXP; e++){ offE[e] = a; a += cnt[e]; }
    }
}

// ---------------- MoE fc: gathered [rows,768] @ w_fc[e] (768x3072) + b, gelu, bf16 out ----------------
__global__ __launch_bounds__(256) void gemm_fc(const float* __restrict__ X,
                                               const float* __restrict__ Wfc,
                                               const float* __restrict__ bfc,
                                               const int* __restrict__ expTok,
                                               const int* __restrict__ cnt,
                                               const int* __restrict__ offE,
                                               unsigned short* __restrict__ H){
    int e = blockIdx.z, tile = blockIdx.y;
    int c = cnt[e];
    int rows = c - tile * BM;
    if (rows <= 0) return;
    __shared__ float As[BK][LP];
    __shared__ float Bs[BK][LP];
    __shared__ int toks[BM];
    int bn = blockIdx.x * BN;
    int tid = threadIdx.x;
    if (tid < BM){
        int idx = tile * BM + tid;
        if (idx >= c) idx = c - 1;
        toks[tid] = expTok[e*NTOK + idx];
    }
    __syncthreads();
    int tx = tid & 15, ty = tid >> 4;
    int arow = tid >> 2, akk = (tid & 3) * 4;
    int bkk = tid >> 4, bn0 = (tid & 15) * 4;
    const float* Bm = Wfc + (size_t)e * DM * FF;
    int tokA = toks[arow];
    float acc[4][4] = {};
    for (int kb = 0; kb < DM; kb += BK){
        float4 av = *(const float4*)&X[(size_t)tokA * DM + kb + akk];
        float4 bv = *(const float4*)&Bm[(size_t)(kb + bkk) * FF + bn + bn0];
        As[akk+0][arow] = av.x; As[akk+1][arow] = av.y;
        As[akk+2][arow] = av.z; As[akk+3][arow] = av.w;
        *(float4*)&Bs[bkk][bn0] = bv;
        __syncthreads();
        #pragma unroll
        for (int kk = 0; kk < BK; kk++){
            float4 a = *(const float4*)&As[kk][ty*4];
            float4 b = *(const float4*)&Bs[kk][tx*4];
            acc[0][0] += a.x*b.x; acc[0][1] += a.x*b.y; acc[0][2] += a.x*b.z; acc[0][3] += a.x*b.w;
            acc[1][0] += a.y*b.x; acc[1][1] += a.y*b.y; acc[1][2] += a.y*b.z; acc[1][3] += a.y*b.w;
            acc[2][0] += a.z*b.x; acc[2][1] += a.z*b.y; acc[2][2] += a.z*b.z; acc[2][3] += a.z*b.w;
            acc[3][0] += a.w*b.x; acc[3][1] += a.w*b.y; acc[3][2] += a.w*b.z; acc[3][3] += a.w*b.w;
        }
        __syncthreads();
    }
    int slot0 = offE[e] + tile * BM;
    float4 bb = *(const float4*)&bfc[(size_t)e*FF + bn + tx*4];
    #pragma unroll
    for (int i = 0; i < 4; i++){
        int mloc = ty*4 + i;
        if (mloc < rows){
            ushort4 o;
            o.x = f2bf(gelu_exact(acc[i][0] + bb.x));
            o.y = f2bf(gelu_exact(acc[i][1] + bb.y));
            o.z = f2bf(gelu_exact(acc[i][2] + bb.z));
            o.w = f2bf(gelu_exact(acc[i][3] + bb.w));
            *(ushort4*)&H[(size_t)(slot0 + mloc) * FF + bn + tx*4] = o;
        }
    }
}

// ---------------- MoE proj: [rows,3072](bf16) @ w_proj[e] (3072x768) -> y ----------------
__global__ __launch_bounds__(256) void gemm_proj(const unsigned short* __restrict__ H,
                                                 const float* __restrict__ Wpr,
                                                 const int* __restrict__ cnt,
                                                 const int* __restrict__ offE,
                                                 float* __restrict__ Y){
    int e = blockIdx.z, tile = blockIdx.y;
    int c = cnt[e];
    int rows = c - tile * BM;
    if (rows <= 0) return;
    __shared__ float As[BK][LP];
    __shared__ float Bs[BK][LP];
    int bn = blockIdx.x * BN;
    int tid = threadIdx.x;
    int tx = tid & 15, ty = tid >> 4;
    int arow = tid >> 2, akk = (tid & 3) * 4;
    int bkk = tid >> 4, bn0 = (tid & 15) * 4;
    int slot0 = offE[e] + tile * BM;
    int ar = arow < rows ? arow : rows - 1;
    const unsigned short* Arow = H + (size_t)(slot0 + ar) * FF;
    const float* Bm = Wpr + (size_t)e * FF * DM;
    float acc[4][4] = {};
    for (int kb = 0; kb < FF; kb += BK){
        ushort4 rv = *(const ushort4*)&Arow[kb + akk];
        float4 bv = *(const float4*)&Bm[(size_t)(kb + bkk) * DM + bn + bn0];
        As[akk+0][arow] = bf2f(rv.x); As[akk+1][arow] = bf2f(rv.y);
        As[akk+2][arow] = bf2f(rv.z); As[akk+3][arow] = bf2f(rv.w);
        *(float4*)&Bs[bkk][bn0] = bv;
        __syncthreads();
        #pragma unroll
        for (int kk = 0; kk < BK; kk++){
            float4 a = *(const float4*)&As[kk][ty*4];
            float4 b = *(const float4*)&Bs[kk][tx*4];
            acc[0][0] += a.x*b.x; acc[0][1] += a.x*b.y; acc[0][2] += a.x*b.z; acc[0][3] += a.x*b.w;
            acc[1][0] += a.y*b.x; acc[1][1] += a.y*b.y; acc[1][2] += a.y*b.z; acc[1][3] += a.y*b.w;
            acc[2][0] += a.z*b.x; acc[2][1] += a.z*b.y; acc[2][2] += a.z*b.z; acc[2][3] += a.z*b.w;
            acc[3][0] += a.w*b.x; acc[3][1] += a.w*b.y; acc[3][2] += a.w*b.z; acc[3][3] += a.w*b.w;
        }
        __syncthreads();
    }
    #pragma unroll
    for (int i = 0; i < 4; i++){
        int mloc = ty*4 + i;
        if (mloc < rows){
            float4 o;
            o.x = acc[i][0]; o.y = acc[i][1]; o.z = acc[i][2]; o.w = acc[i][3];
            *(float4*)&Y[(size_t)(slot0 + mloc) * DM + bn + tx*4] = o;
        }
    }
}

// ---------------- Combine: out = hs + sum_k gate_k * (y_k + b_proj[e_k]) ----------------
__global__ __launch_bounds__(256) void combine_kernel(const float* __restrict__ hs,
                                                      const float* __restrict__ Y,
                                                      const float* __restrict__ bproj,
                                                      const int* __restrict__ tokE,
                                                      const int* __restrict__ tokPos,
                                                      const float* __restrict__ tokGate,
                                                      const int* __restrict__ offE,
                                                      float* __restrict__ out){
    int t = blockIdx.x;
    int e0 = tokE[t*2], e1 = tokE[t*2+1];
    int s0 = offE[e0] + tokPos[t*2];
    int s1 = offE[e1] + tokPos[t*2+1];
    float g0 = tokGate[t*2], g1 = tokGate[t*2+1];
    const float* y0 = Y + (size_t)s0 * DM;
    const float* y1 = Y + (size_t)s1 * DM;
    const float* b0 = bproj + (size_t)e0 * DM;
    const float* b1 = bproj + (size_t)e1 * DM;
    const float* hr = hs + (size_t)t * DM;
    float* orow = out + (size_t)t * DM;
    for (int d = threadIdx.x; d < DM; d += 256){
        orow[d] = hr[d] + g0 * (y0[d] + b0[d]) + g1 * (y1[d] + b1[d]);
    }
}

extern "C" void kernel_launch(void* const* d_in, const int* in_sizes, int n_in,
                              void* d_out, int out_size, void* d_ws, size_t ws_size,
                              hipStream_t stream){
    (void)in_sizes; (void)n_in; (void)out_size; (void)ws_size;
    const float* hidden  = (const float*)d_in[0];
    const float* ln1_g   = (const float*)d_in[1];
    const float* ln1_b   = (const float*)d_in[2];
    const float* w_attn  = (const float*)d_in[3];
    const float* b_attn  = (const float*)d_in[4];
    const float* w_aproj = (const float*)d_in[5];
    const float* b_aproj = (const float*)d_in[6];
    const float* ln2_g   = (const float*)d_in[7];
    const float* ln2_b   = (const float*)d_in[8];
    const float* w_rout  = (const float*)d_in[9];
    const float* w_fc    = (const float*)d_in[10];
    const float* b_fc    = (const float*)d_in[11];
    const float* w_proj  = (const float*)d_in[12];
    const float* b_proj  = (const float*)d_in[13];
    float* out = (float*)d_out;

    char* ws = (char*)d_ws;
    float* x    = (float*)(ws + 0);                     //  6291456 B
    float* hs   = (float*)(ws + 6291456);               //  6291456 B
    float* y    = (float*)(ws + 12582912);              // 12582912 B (also hosts Qb/Kb/Vt pre-MoE)
    float* qkv  = (float*)(ws + 25165824);              // 18874368 B
    float* ctx  = (float*)(ws + 44040192);              //  6291456 B
    unsigned short* hbuf = (unsigned short*)(ws + 25165824); // reuses qkv+ctx (25165824 B)
    // attention bf16 buffers live in y's region (dead until gemm_proj)
    unsigned short* Qb = (unsigned short*)(ws + 12582912);            // 3145728 B
    unsigned short* Kb = (unsigned short*)(ws + 12582912 + 3145728);  // 3145728 B
    unsigned short* Vt = (unsigned short*)(ws + 12582912 + 6291456);  // 3145728 B
    char* rt = ws + 50331648;
    int* cnt      = (int*)(rt + 0);
    int* offE     = (int*)(rt + 32);
    int* expTok   = (int*)(rt + 64);                    // 8*2048*4 = 65536
    int* tokE     = (int*)(rt + 64 + 65536);            // 4096*4
    int* tokPos   = (int*)(rt + 64 + 65536 + 16384);    // 4096*4
    float* tokGate= (float*)(rt + 64 + 65536 + 32768);  // 4096*4

    hipMemsetAsync(cnt, 0, NEXP * sizeof(int), stream);

    ln_kernel<<<NTOK, 256, 0, stream>>>(hidden, ln1_g, ln1_b, x);
    gemm_qkv<<<dim3(TDIM/BN, NTOK/BM), 256, 0, stream>>>(x, w_attn, b_attn, qkv);
    attn_prep<<<NB*NHEAD*16, 256, 0, stream>>>(qkv, Qb, Kb, Vt);
    fattn<<<NB*NHEAD*64, 64, 0, stream>>>(Qb, Kb, Vt, ctx);
    gemm_attnproj<<<dim3(DM/BN, NTOK/BM), 256, 0, stream>>>(ctx, w_aproj, b_aproj, hidden, hs);
    ln_kernel<<<NTOK, 256, 0, stream>>>(hs, ln2_g, ln2_b, x);
    router_kernel<<<NTOK, 64, 0, stream>>>(x, w_rout, cnt, expTok, tokE, tokPos, tokGate);
    offsets_kernel<<<1, 64, 0, stream>>>(cnt, offE);
    gemm_fc<<<dim3(FF/BN, NTOK/BM, NEXP), 256, 0, stream>>>(x, w_fc, b_fc, expTok, cnt, offE, hbuf);
    gemm_proj<<<dim3(DM/BN, NTOK/BM, NEXP), 256, 0, stream>>>(hbuf, w_proj, cnt, offE, y);
    combine_kernel<<<NTOK, 256, 0, stream>>>(hs, y, b_proj, tokE, tokPos, tokGate, offE, out);
}

// Round 4
// 520.198 us; speedup vs baseline: 4.1597x; 2.2091x over previous
//
#include <hip/hip_runtime.h>
#include <hip/hip_bf16.h>
#include <math.h>

#define NB 2
#define SEQ 1024
#define DM 768
#define NHEAD 12
#define HDIM 64
#define NEXP 8
#define FF 3072
#define NTOK (NB*SEQ)          // 2048
#define TDIM (3*DM)            // 2304
#define LNEPS 1e-5f

typedef __attribute__((ext_vector_type(8))) short v8s;
typedef __attribute__((ext_vector_type(4))) float v4f;

// async global->LDS, 16B per lane; dst must be wave-uniform base (lane*16 added by HW)
#define GLDS16(src, dst) \
    __builtin_amdgcn_global_load_lds((const __attribute__((address_space(1))) unsigned int*)(src), \
                                     (__attribute__((address_space(3))) unsigned int*)(dst), 16, 0, 0)

static __device__ __forceinline__ float bf2f(unsigned short u){
    return __uint_as_float(((unsigned)u) << 16);
}
static __device__ __forceinline__ unsigned short f2bf(float f){
    unsigned u = __float_as_uint(f);
    u += 0x7fffu + ((u >> 16) & 1u);   // RNE
    return (unsigned short)(u >> 16);
}
static __device__ __forceinline__ float gelu_exact(float x){
    return 0.5f * x * (1.0f + erff(x * 0.70710678118654752440f));
}

// ---------------- transpose+convert: in fp32 [R][C] -> out bf16 [C][R], per z slice ----------------
__global__ __launch_bounds__(256) void tconv_kernel(const float* __restrict__ in,
                                                    unsigned short* __restrict__ out,
                                                    int R, int C){
    __shared__ float T[32][33];
    size_t base = (size_t)blockIdx.z * R * C;
    int c0 = blockIdx.x * 32, r0 = blockIdx.y * 32;
    int t = threadIdx.x;
    int tr = t >> 3, tc4 = (t & 7) * 4;
    float4 v = *(const float4*)&in[base + (size_t)(r0 + tr) * C + c0 + tc4];
    T[tr][tc4+0] = v.x; T[tr][tc4+1] = v.y; T[tr][tc4+2] = v.z; T[tr][tc4+3] = v.w;
    __syncthreads();
    int oc = t >> 3, or4 = (t & 7) * 4;
    ushort4 o;
    o.x = f2bf(T[or4+0][oc]); o.y = f2bf(T[or4+1][oc]);
    o.z = f2bf(T[or4+2][oc]); o.w = f2bf(T[or4+3][oc]);
    *(ushort4*)&out[base + (size_t)(c0 + oc) * R + r0 + or4] = o;
}

// ---------------- LayerNorm: one block per row; writes fp32 + bf16 ----------------
__global__ __launch_bounds__(256) void ln_kernel(const float* __restrict__ in,
                                                 const float* __restrict__ g,
                                                 const float* __restrict__ b,
                                                 float* __restrict__ out,
                                                 unsigned short* __restrict__ outb){
    int t = blockIdx.x;
    const float* row = in + (size_t)t * DM;
    int tid = threadIdx.x;
    float v0 = row[tid], v1 = row[tid + 256], v2 = row[tid + 512];
    float s  = v0 + v1 + v2;
    float ss = v0*v0 + v1*v1 + v2*v2;
    for (int off = 32; off; off >>= 1){
        s  += __shfl_down(s, off);
        ss += __shfl_down(ss, off);
    }
    __shared__ float ls[4], lss[4];
    int wid = tid >> 6, lane = tid & 63;
    if (lane == 0){ ls[wid] = s; lss[wid] = ss; }
    __syncthreads();
    if (tid == 0){
        float a = ls[0] + ls[1] + ls[2] + ls[3];
        float c = lss[0] + lss[1] + lss[2] + lss[3];
        float mu = a / (float)DM;
        float var = c / (float)DM - mu * mu;
        ls[0] = mu; lss[0] = rsqrtf(var + LNEPS);
    }
    __syncthreads();
    float mu = ls[0], rs = lss[0];
    float* orow = out + (size_t)t * DM;
    unsigned short* obrow = outb + (size_t)t * DM;
    float o0 = (v0 - mu) * rs * g[tid]       + b[tid];
    float o1 = (v1 - mu) * rs * g[tid + 256] + b[tid + 256];
    float o2 = (v2 - mu) * rs * g[tid + 512] + b[tid + 512];
    orow[tid] = o0; orow[tid+256] = o1; orow[tid+512] = o2;
    obrow[tid] = f2bf(o0); obrow[tid+256] = f2bf(o1); obrow[tid+512] = f2bf(o2);
}

// ================= MFMA GEMM core pieces (128x128 tile, BK=32, 4 waves) =================
// A: [M][K] bf16 row-major (K-contig). B: [N][K] bf16 (pre-transposed, K-contig).
// C[m][n] = sum_k A[m][k]*B[n][k].  C/D frag: row = quad*4+reg, col = l15.

// ---------------- QKV: Xb[2048][768] @ Wab[2304][768] + bias -> qkv fp32 ----------------
__global__ __launch_bounds__(256) void mm_qkv(const unsigned short* __restrict__ Ab,
                                              const unsigned short* __restrict__ Bb,
                                              const float* __restrict__ bias,
                                              float* __restrict__ C){
    __shared__ __align__(16) unsigned short As[128*32];
    __shared__ __align__(16) unsigned short Bs[128*32];
    int bm = blockIdx.y * 128, bn = blockIdx.x * 128;
    int tid = threadIdx.x, wave = tid >> 6, lane = tid & 63;
    int quad = lane >> 4, l15 = lane & 15;
    int wm = wave >> 1, wn = wave & 1;
    int lrow = lane >> 2, lchunk = (lane & 3) * 8;
    const unsigned short* aS0 = Ab + (size_t)(bm +      wave*16 + lrow) * 768 + lchunk;
    const unsigned short* aS1 = Ab + (size_t)(bm + 64 + wave*16 + lrow) * 768 + lchunk;
    const unsigned short* bS0 = Bb + (size_t)(bn +      wave*16 + lrow) * 768 + lchunk;
    const unsigned short* bS1 = Bb + (size_t)(bn + 64 + wave*16 + lrow) * 768 + lchunk;
    unsigned short* aD0 = &As[(     wave*16)*32];
    unsigned short* aD1 = &As[(64 + wave*16)*32];
    unsigned short* bD0 = &Bs[(     wave*16)*32];
    unsigned short* bD1 = &Bs[(64 + wave*16)*32];
    v4f acc[4][4];
    #pragma unroll
    for (int i = 0; i < 4; i++)
        #pragma unroll
        for (int j = 0; j < 4; j++) acc[i][j] = (v4f){0.f,0.f,0.f,0.f};
    for (int kt = 0; kt < 768/32; kt++){
        int kb = kt * 32;
        GLDS16(aS0 + kb, aD0); GLDS16(aS1 + kb, aD1);
        GLDS16(bS0 + kb, bD0); GLDS16(bS1 + kb, bD1);
        __syncthreads();
        v8s a[4], b[4];
        #pragma unroll
        for (int i = 0; i < 4; i++){
            a[i] = *(const v8s*)&As[(wm*64 + i*16 + l15)*32 + quad*8];
            b[i] = *(const v8s*)&Bs[(wn*64 + i*16 + l15)*32 + quad*8];
        }
        #pragma unroll
        for (int mt = 0; mt < 4; mt++)
            #pragma unroll
            for (int nt = 0; nt < 4; nt++)
                acc[mt][nt] = __builtin_amdgcn_mfma_f32_16x16x32_bf16(a[mt], b[nt], acc[mt][nt], 0, 0, 0);
        __syncthreads();
    }
    #pragma unroll
    for (int nt = 0; nt < 4; nt++){
        int n = bn + wn*64 + nt*16 + l15;
        float bb = bias[n];
        #pragma unroll
        for (int mt = 0; mt < 4; mt++){
            int m = bm + wm*64 + mt*16 + quad*4;
            #pragma unroll
            for (int r = 0; r < 4; r++)
                C[(size_t)(m + r) * TDIM + n] = acc[mt][nt][r] + bb;
        }
    }
}

// ---------------- attn-proj: ctxb[2048][768] @ Wapb[768][768] + bias + residual -> hs fp32 ----------------
__global__ __launch_bounds__(256) void mm_attnproj(const unsigned short* __restrict__ Ab,
                                                   const unsigned short* __restrict__ Bb,
                                                   const float* __restrict__ bias,
                                                   const float* __restrict__ res,
                                                   float* __restrict__ C){
    __shared__ __align__(16) unsigned short As[128*32];
    __shared__ __align__(16) unsigned short Bs[128*32];
    int bm = blockIdx.y * 128, bn = blockIdx.x * 128;
    int tid = threadIdx.x, wave = tid >> 6, lane = tid & 63;
    int quad = lane >> 4, l15 = lane & 15;
    int wm = wave >> 1, wn = wave & 1;
    int lrow = lane >> 2, lchunk = (lane & 3) * 8;
    const unsigned short* aS0 = Ab + (size_t)(bm +      wave*16 + lrow) * 768 + lchunk;
    const unsigned short* aS1 = Ab + (size_t)(bm + 64 + wave*16 + lrow) * 768 + lchunk;
    const unsigned short* bS0 = Bb + (size_t)(bn +      wave*16 + lrow) * 768 + lchunk;
    const unsigned short* bS1 = Bb + (size_t)(bn + 64 + wave*16 + lrow) * 768 + lchunk;
    unsigned short* aD0 = &As[(     wave*16)*32];
    unsigned short* aD1 = &As[(64 + wave*16)*32];
    unsigned short* bD0 = &Bs[(     wave*16)*32];
    unsigned short* bD1 = &Bs[(64 + wave*16)*32];
    v4f acc[4][4];
    #pragma unroll
    for (int i = 0; i < 4; i++)
        #pragma unroll
        for (int j = 0; j < 4; j++) acc[i][j] = (v4f){0.f,0.f,0.f,0.f};
    for (int kt = 0; kt < 768/32; kt++){
        int kb = kt * 32;
        GLDS16(aS0 + kb, aD0); GLDS16(aS1 + kb, aD1);
        GLDS16(bS0 + kb, bD0); GLDS16(bS1 + kb, bD1);
        __syncthreads();
        v8s a[4], b[4];
        #pragma unroll
        for (int i = 0; i < 4; i++){
            a[i] = *(const v8s*)&As[(wm*64 + i*16 + l15)*32 + quad*8];
            b[i] = *(const v8s*)&Bs[(wn*64 + i*16 + l15)*32 + quad*8];
        }
        #pragma unroll
        for (int mt = 0; mt < 4; mt++)
            #pragma unroll
            for (int nt = 0; nt < 4; nt++)
                acc[mt][nt] = __builtin_amdgcn_mfma_f32_16x16x32_bf16(a[mt], b[nt], acc[mt][nt], 0, 0, 0);
        __syncthreads();
    }
    #pragma unroll
    for (int nt = 0; nt < 4; nt++){
        int n = bn + wn*64 + nt*16 + l15;
        float bb = bias[n];
        #pragma unroll
        for (int mt = 0; mt < 4; mt++){
            int m = bm + wm*64 + mt*16 + quad*4;
            #pragma unroll
            for (int r = 0; r < 4; r++)
                C[(size_t)(m + r) * DM + n] = acc[mt][nt][r] + bb + res[(size_t)(m + r) * DM + n];
        }
    }
}

// ---------------- MoE fc: gathered Xb rows @ Wfcb[e][3072][768] + bias, gelu -> H bf16 ----------------
__global__ __launch_bounds__(256) void mm_fc(const unsigned short* __restrict__ Xb,
                                             const unsigned short* __restrict__ Wb,
                                             const float* __restrict__ bfc,
                                             const int* __restrict__ expTok,
                                             const int* __restrict__ cnt,
                                             const int* __restrict__ offE,
                                             unsigned short* __restrict__ H){
    int e = blockIdx.z, tile = blockIdx.y;
    int c = cnt[e];
    int rows = c - tile * 128;
    if (rows <= 0) return;
    __shared__ __align__(16) unsigned short As[128*32];
    __shared__ __align__(16) unsigned short Bs[128*32];
    __shared__ int toks[128];
    int bn = blockIdx.x * 128;
    int tid = threadIdx.x, wave = tid >> 6, lane = tid & 63;
    if (tid < 128){
        int idx = tile * 128 + tid;
        if (idx >= c) idx = c - 1;
        toks[tid] = expTok[e * NTOK + idx];
    }
    __syncthreads();
    int quad = lane >> 4, l15 = lane & 15;
    int wm = wave >> 1, wn = wave & 1;
    int lrow = lane >> 2, lchunk = (lane & 3) * 8;
    int tok0 = toks[     wave*16 + lrow];
    int tok1 = toks[64 + wave*16 + lrow];
    const unsigned short* Be = Wb + (size_t)e * FF * DM;
    const unsigned short* aS0 = Xb + (size_t)tok0 * 768 + lchunk;
    const unsigned short* aS1 = Xb + (size_t)tok1 * 768 + lchunk;
    const unsigned short* bS0 = Be + (size_t)(bn +      wave*16 + lrow) * 768 + lchunk;
    const unsigned short* bS1 = Be + (size_t)(bn + 64 + wave*16 + lrow) * 768 + lchunk;
    unsigned short* aD0 = &As[(     wave*16)*32];
    unsigned short* aD1 = &As[(64 + wave*16)*32];
    unsigned short* bD0 = &Bs[(     wave*16)*32];
    unsigned short* bD1 = &Bs[(64 + wave*16)*32];
    v4f acc[4][4];
    #pragma unroll
    for (int i = 0; i < 4; i++)
        #pragma unroll
        for (int j = 0; j < 4; j++) acc[i][j] = (v4f){0.f,0.f,0.f,0.f};
    for (int kt = 0; kt < 768/32; kt++){
        int kb = kt * 32;
        GLDS16(aS0 + kb, aD0); GLDS16(aS1 + kb, aD1);
        GLDS16(bS0 + kb, bD0); GLDS16(bS1 + kb, bD1);
        __syncthreads();
        v8s a[4], b[4];
        #pragma unroll
        for (int i = 0; i < 4; i++){
            a[i] = *(const v8s*)&As[(wm*64 + i*16 + l15)*32 + quad*8];
            b[i] = *(const v8s*)&Bs[(wn*64 + i*16 + l15)*32 + quad*8];
        }
        #pragma unroll
        for (int mt = 0; mt < 4; mt++)
            #pragma unroll
            for (int nt = 0; nt < 4; nt++)
                acc[mt][nt] = __builtin_amdgcn_mfma_f32_16x16x32_bf16(a[mt], b[nt], acc[mt][nt], 0, 0, 0);
        __syncthreads();
    }
    int slot0 = offE[e] + tile * 128;
    #pragma unroll
    for (int nt = 0; nt < 4; nt++){
        int n = bn + wn*64 + nt*16 + l15;
        float bb = bfc[(size_t)e * FF + n];
        #pragma unroll
        for (int mt = 0; mt < 4; mt++){
            int ml = wm*64 + mt*16 + quad*4;
            #pragma unroll
            for (int r = 0; r < 4; r++)
                if (ml + r < rows)
                    H[(size_t)(slot0 + ml + r) * FF + n] = f2bf(gelu_exact(acc[mt][nt][r] + bb));
        }
    }
}

// ---------------- MoE proj: H[rows][3072] @ Wprb[e][768][3072] -> Y fp32 ----------------
__global__ __launch_bounds__(256) void mm_proj(const unsigned short* __restrict__ H,
                                               const unsigned short* __restrict__ Wb,
                                               const int* __restrict__ cnt,
                                               const int* __restrict__ offE,
                                               float* __restrict__ Y){
    int e = blockIdx.z, tile = blockIdx.y;
    int c = cnt[e];
    int rows = c - tile * 128;
    if (rows <= 0) return;
    __shared__ __align__(16) unsigned short As[128*32];
    __shared__ __align__(16) unsigned short Bs[128*32];
    int bn = blockIdx.x * 128;
    int tid = threadIdx.x, wave = tid >> 6, lane = tid & 63;
    int quad = lane >> 4, l15 = lane & 15;
    int wm = wave >> 1, wn = wave & 1;
    int lrow = lane >> 2, lchunk = (lane & 3) * 8;
    int slot0 = offE[e] + tile * 128;
    int rl0 =      wave*16 + lrow; if (rl0 > rows - 1) rl0 = rows - 1;
    int rl1 = 64 + wave*16 + lrow; if (rl1 > rows - 1) rl1 = rows - 1;
    const unsigned short* Be = Wb + (size_t)e * DM * FF;
    const unsigned short* aS0 = H + (size_t)(slot0 + rl0) * FF + lchunk;
    const unsigned short* aS1 = H + (size_t)(slot0 + rl1) * FF + lchunk;
    const unsigned short* bS0 = Be + (size_t)(bn +      wave*16 + lrow) * FF + lchunk;
    const unsigned short* bS1 = Be + (size_t)(bn + 64 + wave*16 + lrow) * FF + lchunk;
    unsigned short* aD0 = &As[(     wave*16)*32];
    unsigned short* aD1 = &As[(64 + wave*16)*32];
    unsigned short* bD0 = &Bs[(     wave*16)*32];
    unsigned short* bD1 = &Bs[(64 + wave*16)*32];
    v4f acc[4][4];
    #pragma unroll
    for (int i = 0; i < 4; i++)
        #pragma unroll
        for (int j = 0; j < 4; j++) acc[i][j] = (v4f){0.f,0.f,0.f,0.f};
    for (int kt = 0; kt < FF/32; kt++){
        int kb = kt * 32;
        GLDS16(aS0 + kb, aD0); GLDS16(aS1 + kb, aD1);
        GLDS16(bS0 + kb, bD0); GLDS16(bS1 + kb, bD1);
        __syncthreads();
        v8s a[4], b[4];
        #pragma unroll
        for (int i = 0; i < 4; i++){
            a[i] = *(const v8s*)&As[(wm*64 + i*16 + l15)*32 + quad*8];
            b[i] = *(const v8s*)&Bs[(wn*64 + i*16 + l15)*32 + quad*8];
        }
        #pragma unroll
        for (int mt = 0; mt < 4; mt++)
            #pragma unroll
            for (int nt = 0; nt < 4; nt++)
                acc[mt][nt] = __builtin_amdgcn_mfma_f32_16x16x32_bf16(a[mt], b[nt], acc[mt][nt], 0, 0, 0);
        __syncthreads();
    }
    #pragma unroll
    for (int nt = 0; nt < 4; nt++){
        int n = bn + wn*64 + nt*16 + l15;
        #pragma unroll
        for (int mt = 0; mt < 4; mt++){
            int ml = wm*64 + mt*16 + quad*4;
            #pragma unroll
            for (int r = 0; r < 4; r++)
                if (ml + r < rows)
                    Y[(size_t)(slot0 + ml + r) * DM + n] = acc[mt][nt][r];
        }
    }
}

// ---------------- Attention prep: qkv f32 -> Qb/Kb bf16 [bh][s][64], Vt bf16 [bh][d][s] ----------------
__global__ __launch_bounds__(256) void attn_prep(const float* __restrict__ qkv,
                                                 unsigned short* __restrict__ Qb,
                                                 unsigned short* __restrict__ Kb,
                                                 unsigned short* __restrict__ Vt){
    int bi = blockIdx.x;
    int c = bi & 15, bh = bi >> 4;
    int h = bh % NHEAD, b = bh / NHEAD;
    __shared__ float vt[64][65];
    int tid = threadIdx.x;
    int row = tid >> 2, ds = (tid & 3) * 16;
    const float* base = qkv + (size_t)(b*SEQ + c*64 + row) * TDIM + h*HDIM + ds;
    size_t qkrow = ((size_t)bh*SEQ + c*64 + row) * HDIM + ds;
    #pragma unroll
    for (int j = 0; j < 16; j += 4){
        float4 qv = *(const float4*)(base + j);
        ushort4 qo;
        qo.x = f2bf(qv.x*0.125f); qo.y = f2bf(qv.y*0.125f);
        qo.z = f2bf(qv.z*0.125f); qo.w = f2bf(qv.w*0.125f);
        *(ushort4*)&Qb[qkrow + j] = qo;
        float4 kv = *(const float4*)(base + DM + j);
        ushort4 ko;
        ko.x = f2bf(kv.x); ko.y = f2bf(kv.y); ko.z = f2bf(kv.z); ko.w = f2bf(kv.w);
        *(ushort4*)&Kb[qkrow + j] = ko;
        float4 vv = *(const float4*)(base + 2*DM + j);
        vt[row][ds+j+0] = vv.x; vt[row][ds+j+1] = vv.y;
        vt[row][ds+j+2] = vv.z; vt[row][ds+j+3] = vv.w;
    }
    __syncthreads();
    int d = tid >> 2, ks = (tid & 3) * 16;
    size_t vrow = ((size_t)bh*HDIM + d) * SEQ + c*64 + ks;
    #pragma unroll
    for (int j = 0; j < 16; j += 4){
        ushort4 o;
        o.x = f2bf(vt[ks+j+0][d]); o.y = f2bf(vt[ks+j+1][d]);
        o.z = f2bf(vt[ks+j+2][d]); o.w = f2bf(vt[ks+j+3][d]);
        *(ushort4*)&Vt[vrow + j] = o;
    }
}

// ---------------- Flash attention: one wave per (bh, 16-query tile); bf16 ctx out ----------------
__global__ __launch_bounds__(64) void fattn(const unsigned short* __restrict__ Qb,
                                            const unsigned short* __restrict__ Kb,
                                            const unsigned short* __restrict__ Vt,
                                            unsigned short* __restrict__ ctxb){
    int bh = blockIdx.x >> 6;
    int q0 = (63 - (blockIdx.x & 63)) * 16;
    int h = bh % NHEAD, b = bh / NHEAD;
    int lane = threadIdx.x;
    int quad = lane >> 4, l15 = lane & 15;

    __shared__ __align__(16) unsigned short Plds[16*32];

    const unsigned short* qp = Qb + ((size_t)bh*SEQ + q0 + l15) * HDIM + quad*8;
    v8s qa0 = *(const v8s*)qp;
    v8s qa1 = *(const v8s*)(qp + 32);

    v4f o0 = {0,0,0,0}, o1 = {0,0,0,0}, o2 = {0,0,0,0}, o3 = {0,0,0,0};
    float mrow[4] = {-1e30f,-1e30f,-1e30f,-1e30f};
    float lrow[4] = {0,0,0,0};

    int nch = (q0 + 16 + 31) >> 5;
    for (int ch = 0; ch < nch; ch++){
        int kt = ch * 32;
        const unsigned short* kp = Kb + ((size_t)bh*SEQ + kt + l15) * HDIM + quad*8;
        v8s kb0l = *(const v8s*)kp;
        v8s kb0h = *(const v8s*)(kp + 32);
        v8s kb1l = *(const v8s*)(kp + 16*HDIM);
        v8s kb1h = *(const v8s*)(kp + 16*HDIM + 32);
        v4f s0 = {0,0,0,0}, s1 = {0,0,0,0};
        s0 = __builtin_amdgcn_mfma_f32_16x16x32_bf16(qa0, kb0l, s0, 0, 0, 0);
        s0 = __builtin_amdgcn_mfma_f32_16x16x32_bf16(qa1, kb0h, s0, 0, 0, 0);
        s1 = __builtin_amdgcn_mfma_f32_16x16x32_bf16(qa0, kb1l, s1, 0, 0, 0);
        s1 = __builtin_amdgcn_mfma_f32_16x16x32_bf16(qa1, kb1h, s1, 0, 0, 0);

        int key0 = kt + l15, key1 = kt + 16 + l15;
        float alpha[4];
        #pragma unroll
        for (int r = 0; r < 4; r++){
            int qrow = q0 + quad*4 + r;
            float v0 = (key0 <= qrow) ? s0[r] : -1e30f;
            float v1 = (key1 <= qrow) ? s1[r] : -1e30f;
            float mx = fmaxf(v0, v1);
            mx = fmaxf(mx, __shfl_xor(mx, 1));
            mx = fmaxf(mx, __shfl_xor(mx, 2));
            mx = fmaxf(mx, __shfl_xor(mx, 4));
            mx = fmaxf(mx, __shfl_xor(mx, 8));
            float mn = fmaxf(mrow[r], mx);
            alpha[r] = __expf(mrow[r] - mn);
            float p0 = __expf(v0 - mn);
            float p1 = __expf(v1 - mn);
            float ps = p0 + p1;
            ps += __shfl_xor(ps, 1);
            ps += __shfl_xor(ps, 2);
            ps += __shfl_xor(ps, 4);
            ps += __shfl_xor(ps, 8);
            lrow[r] = lrow[r] * alpha[r] + ps;
            mrow[r] = mn;
            Plds[(quad*4 + r)*32 + l15]      = f2bf(p0);
            Plds[(quad*4 + r)*32 + 16 + l15] = f2bf(p1);
        }
        #pragma unroll
        for (int r = 0; r < 4; r++){
            o0[r] *= alpha[r]; o1[r] *= alpha[r];
            o2[r] *= alpha[r]; o3[r] *= alpha[r];
        }
        __syncthreads();
        v8s pa = *(const v8s*)&Plds[l15*32 + quad*8];
        const unsigned short* vp = Vt + ((size_t)bh*HDIM + l15) * SEQ + kt + quad*8;
        v8s vb0 = *(const v8s*)vp;
        v8s vb1 = *(const v8s*)(vp + 16*SEQ);
        v8s vb2 = *(const v8s*)(vp + 32*SEQ);
        v8s vb3 = *(const v8s*)(vp + 48*SEQ);
        o0 = __builtin_amdgcn_mfma_f32_16x16x32_bf16(pa, vb0, o0, 0, 0, 0);
        o1 = __builtin_amdgcn_mfma_f32_16x16x32_bf16(pa, vb1, o1, 0, 0, 0);
        o2 = __builtin_amdgcn_mfma_f32_16x16x32_bf16(pa, vb2, o2, 0, 0, 0);
        o3 = __builtin_amdgcn_mfma_f32_16x16x32_bf16(pa, vb3, o3, 0, 0, 0);
        __syncthreads();
    }
    #pragma unroll
    for (int r = 0; r < 4; r++){
        float inv = 1.0f / lrow[r];
        size_t orow = (size_t)(b*SEQ + q0 + quad*4 + r) * DM + h*HDIM;
        ctxb[orow + l15]      = f2bf(o0[r] * inv);
        ctxb[orow + 16 + l15] = f2bf(o1[r] * inv);
        ctxb[orow + 32 + l15] = f2bf(o2[r] * inv);
        ctxb[orow + 48 + l15] = f2bf(o3[r] * inv);
    }
}

// ---------------- Router: one wave per token ----------------
__global__ __launch_bounds__(64) void router_kernel(const float* __restrict__ x2,
                                                    const float* __restrict__ wr,
                                                    int* __restrict__ cnt,
                                                    int* __restrict__ expTok,
                                                    int* __restrict__ tokE,
                                                    int* __restrict__ tokPos,
                                                    float* __restrict__ tokGate){
    int t = blockIdx.x;
    int lane = threadIdx.x;
    const float* xr = x2 + (size_t)t * DM;
    float acc[NEXP] = {};
    for (int d = lane; d < DM; d += 64){
        float xv = xr[d];
        #pragma unroll
        for (int e = 0; e < NEXP; e++) acc[e] += xv * wr[e*DM + d];
    }
    #pragma unroll
    for (int e = 0; e < NEXP; e++)
        for (int off = 32; off; off >>= 1) acc[e] += __shfl_xor(acc[e], off);
    if (lane == 0){
        int i0 = 0; float m0 = acc[0];
        #pragma unroll
        for (int e = 1; e < NEXP; e++) if (acc[e] > m0){ m0 = acc[e]; i0 = e; }
        int i1 = -1; float m1 = -INFINITY;
        #pragma unroll
        for (int e = 0; e < NEXP; e++) if (e != i0 && acc[e] > m1){ m1 = acc[e]; i1 = e; }
        float mx = fmaxf(m0, m1);
        float e0 = __expf(m0 - mx), e1 = __expf(m1 - mx);
        float inv = 1.0f / (e0 + e1);
        int p0 = atomicAdd(&cnt[i0], 1);
        int p1 = atomicAdd(&cnt[i1], 1);
        expTok[i0*NTOK + p0] = t;
        expTok[i1*NTOK + p1] = t;
        tokE[t*2]   = i0; tokE[t*2+1]   = i1;
        tokPos[t*2] = p0; tokPos[t*2+1] = p1;
        tokGate[t*2]   = e0 * inv;
        tokGate[t*2+1] = e1 * inv;
    }
}

__global__ void offsets_kernel(const int* __restrict__ cnt, int* __restrict__ offE){
    if (threadIdx.x == 0 && blockIdx.x == 0){
        int a = 0;
        for (int e = 0; e < NEXP; e++){ offE[e] = a; a += cnt[e]; }
    }
}

// ---------------- Combine: out = hs + sum_k gate_k * (y_k + b_proj[e_k]) ----------------
__global__ __launch_bounds__(256) void combine_kernel(const float* __restrict__ hs,
                                                      const float* __restrict__ Y,
                                                      const float* __restrict__ bproj,
                                                      const int* __restrict__ tokE,
                                                      const int* __restrict__ tokPos,
                                                      const float* __restrict__ tokGate,
                                                      const int* __restrict__ offE,
                                                      float* __restrict__ out){
    int t = blockIdx.x;
    int e0 = tokE[t*2], e1 = tokE[t*2+1];
    int s0 = offE[e0] + tokPos[t*2];
    int s1 = offE[e1] + tokPos[t*2+1];
    float g0 = tokGate[t*2], g1 = tokGate[t*2+1];
    const float* y0 = Y + (size_t)s0 * DM;
    const float* y1 = Y + (size_t)s1 * DM;
    const float* b0 = bproj + (size_t)e0 * DM;
    const float* b1 = bproj + (size_t)e1 * DM;
    const float* hr = hs + (size_t)t * DM;
    float* orow = out + (size_t)t * DM;
    for (int d = threadIdx.x; d < DM; d += 256){
        orow[d] = hr[d] + g0 * (y0[d] + b0[d]) + g1 * (y1[d] + b1[d]);
    }
}

extern "C" void kernel_launch(void* const* d_in, const int* in_sizes, int n_in,
                              void* d_out, int out_size, void* d_ws, size_t ws_size,
                              hipStream_t stream){
    (void)in_sizes; (void)n_in; (void)out_size; (void)ws_size;
    const float* hidden  = (const float*)d_in[0];
    const float* ln1_g   = (const float*)d_in[1];
    const float* ln1_b   = (const float*)d_in[2];
    const float* w_attn  = (const float*)d_in[3];
    const float* b_attn  = (const float*)d_in[4];
    const float* w_aproj = (const float*)d_in[5];
    const float* b_aproj = (const float*)d_in[6];
    const float* ln2_g   = (const float*)d_in[7];
    const float* ln2_b   = (const float*)d_in[8];
    const float* w_rout  = (const float*)d_in[9];
    const float* w_fc    = (const float*)d_in[10];
    const float* b_fc    = (const float*)d_in[11];
    const float* w_proj  = (const float*)d_in[12];
    const float* b_proj  = (const float*)d_in[13];
    float* out = (float*)d_out;

    char* ws = (char*)d_ws;
    // layout (bytes); Y overlays x+Vt+ctxb; H overlays qkv+Qb+Kb
    float*          x    = (float*)(ws + 0);                      //  6,291,456
    unsigned short* Vt   = (unsigned short*)(ws + 6291456);       //  3,145,728
    unsigned short* ctxb = (unsigned short*)(ws + 9437184);       //  3,145,728
    float*          Y    = (float*)(ws + 0);                      // 12,582,912 overlay
    float*          hs   = (float*)(ws + 12582912);               //  6,291,456
    unsigned short* xb   = (unsigned short*)(ws + 18874368);      //  3,145,728
    float*          qkv  = (float*)(ws + 22020096);               // 18,874,368
    unsigned short* Qb   = (unsigned short*)(ws + 40894464);      //  3,145,728
    unsigned short* Kb   = (unsigned short*)(ws + 44040192);      //  3,145,728
    unsigned short* H    = (unsigned short*)(ws + 22020096);      // 25,165,824 overlay
    unsigned short* Wab  = (unsigned short*)(ws + 47185920);      //  3,538,944
    unsigned short* Wapb = (unsigned short*)(ws + 50724864);      //  1,179,648
    unsigned short* Wfcb = (unsigned short*)(ws + 51904512);      // 37,748,736
    unsigned short* Wprb = (unsigned short*)(ws + 89653248);      // 37,748,736
    char* rt = ws + 127401984;
    int* cnt      = (int*)(rt + 0);
    int* offE     = (int*)(rt + 64);
    int* expTok   = (int*)(rt + 128);                   // 65,536
    int* tokE     = (int*)(rt + 128 + 65536);           // 16,384
    int* tokPos   = (int*)(rt + 128 + 81920);           // 16,384
    float* tokGate= (float*)(rt + 128 + 98304);         // 16,384

    hipMemsetAsync(cnt, 0, NEXP * sizeof(int), stream);

    // weight transpose+convert to bf16 [N][K]
    tconv_kernel<<<dim3(TDIM/32, DM/32, 1), 256, 0, stream>>>(w_attn, Wab, DM, TDIM);
    tconv_kernel<<<dim3(DM/32, DM/32, 1), 256, 0, stream>>>(w_aproj, Wapb, DM, DM);
    tconv_kernel<<<dim3(FF/32, DM/32, NEXP), 256, 0, stream>>>(w_fc, Wfcb, DM, FF);
    tconv_kernel<<<dim3(DM/32, FF/32, NEXP), 256, 0, stream>>>(w_proj, Wprb, FF, DM);

    ln_kernel<<<NTOK, 256, 0, stream>>>(hidden, ln1_g, ln1_b, x, xb);
    mm_qkv<<<dim3(TDIM/128, NTOK/128), 256, 0, stream>>>(xb, Wab, b_attn, qkv);
    attn_prep<<<NB*NHEAD*16, 256, 0, stream>>>(qkv, Qb, Kb, Vt);
    fattn<<<NB*NHEAD*64, 64, 0, stream>>>(Qb, Kb, Vt, ctxb);
    mm_attnproj<<<dim3(DM/128, NTOK/128), 256, 0, stream>>>(ctxb, Wapb, b_aproj, hidden, hs);
    ln_kernel<<<NTOK, 256, 0, stream>>>(hs, ln2_g, ln2_b, x, xb);
    router_kernel<<<NTOK, 64, 0, stream>>>(x, w_rout, cnt, expTok, tokE, tokPos, tokGate);
    offsets_kernel<<<1, 64, 0, stream>>>(cnt, offE);
    mm_fc<<<dim3(FF/128, NTOK/128, NEXP), 256, 0, stream>>>(xb, Wfcb, b_fc, expTok, cnt, offE, H);
    mm_proj<<<dim3(DM/128, NTOK/128, NEXP), 256, 0, stream>>>(H, Wprb, cnt, offE, Y);
    combine_kernel<<<NTOK, 256, 0, stream>>>(hs, Y, b_proj, tokE, tokPos, tokGate, offE, out);
}

// Round 5
// 481.840 us; speedup vs baseline: 4.4909x; 1.0796x over previous
//
#include <hip/hip_runtime.h>
#include <hip/hip_bf16.h>
#include <math.h>

#define NB 2
#define SEQ 1024
#define DM 768
#define NHEAD 12
#define HDIM 64
#define NEXP 8
#define FF 3072
#define NTOK (NB*SEQ)          // 2048
#define TDIM (3*DM)            // 2304
#define LNEPS 1e-5f
#define NSLOT (NTOK*2)         // 4096

typedef __attribute__((ext_vector_type(8))) short v8s;
typedef __attribute__((ext_vector_type(4))) float v4f;

// async global->LDS, 16B per lane; dst wave-uniform base (lane*16 added by HW)
#define GLDS16(src, dst) \
    __builtin_amdgcn_global_load_lds((const __attribute__((address_space(1))) unsigned int*)(src), \
                                     (__attribute__((address_space(3))) unsigned int*)(dst), 16, 0, 0)

static __device__ __forceinline__ float bf2f(unsigned short u){
    return __uint_as_float(((unsigned)u) << 16);
}
static __device__ __forceinline__ unsigned short f2bf(float f){
    unsigned u = __float_as_uint(f);
    u += 0x7fffu + ((u >> 16) & 1u);   // RNE
    return (unsigned short)(u >> 16);
}
static __device__ __forceinline__ float gelu_exact(float x){
    return 0.5f * x * (1.0f + erff(x * 0.70710678118654752440f));
}

// ---------------- transpose+convert: in fp32 [R][C] -> out bf16 [C][R], per z slice ----------------
__global__ __launch_bounds__(256) void tconv_kernel(const float* __restrict__ in,
                                                    unsigned short* __restrict__ out,
                                                    int R, int C){
    __shared__ float T[32][33];
    size_t base = (size_t)blockIdx.z * R * C;
    int c0 = blockIdx.x * 32, r0 = blockIdx.y * 32;
    int t = threadIdx.x;
    int tr = t >> 3, tc4 = (t & 7) * 4;
    float4 v = *(const float4*)&in[base + (size_t)(r0 + tr) * C + c0 + tc4];
    T[tr][tc4+0] = v.x; T[tr][tc4+1] = v.y; T[tr][tc4+2] = v.z; T[tr][tc4+3] = v.w;
    __syncthreads();
    int oc = t >> 3, or4 = (t & 7) * 4;
    ushort4 o;
    o.x = f2bf(T[or4+0][oc]); o.y = f2bf(T[or4+1][oc]);
    o.z = f2bf(T[or4+2][oc]); o.w = f2bf(T[or4+3][oc]);
    *(ushort4*)&out[base + (size_t)(c0 + oc) * R + r0 + or4] = o;
}

// ---------------- LayerNorm (bf16 out only) ----------------
__global__ __launch_bounds__(256) void ln_b(const float* __restrict__ in,
                                            const float* __restrict__ g,
                                            const float* __restrict__ b,
                                            unsigned short* __restrict__ outb){
    int t = blockIdx.x;
    const float* row = in + (size_t)t * DM;
    int tid = threadIdx.x;
    float v0 = row[tid], v1 = row[tid + 256], v2 = row[tid + 512];
    float s  = v0 + v1 + v2;
    float ss = v0*v0 + v1*v1 + v2*v2;
    for (int off = 32; off; off >>= 1){
        s  += __shfl_down(s, off);
        ss += __shfl_down(ss, off);
    }
    __shared__ float ls[4], lss[4];
    int wid = tid >> 6, lane = tid & 63;
    if (lane == 0){ ls[wid] = s; lss[wid] = ss; }
    __syncthreads();
    if (tid == 0){
        float a = ls[0] + ls[1] + ls[2] + ls[3];
        float c = lss[0] + lss[1] + lss[2] + lss[3];
        float mu = a / (float)DM;
        float var = c / (float)DM - mu * mu;
        ls[0] = mu; lss[0] = rsqrtf(var + LNEPS);
    }
    __syncthreads();
    float mu = ls[0], rs = lss[0];
    unsigned short* obrow = outb + (size_t)t * DM;
    obrow[tid]     = f2bf((v0 - mu) * rs * g[tid]       + b[tid]);
    obrow[tid+256] = f2bf((v1 - mu) * rs * g[tid + 256] + b[tid + 256]);
    obrow[tid+512] = f2bf((v2 - mu) * rs * g[tid + 512] + b[tid + 512]);
}

// ---------------- LayerNorm + router fused: bf16 out + top-2 expert routing ----------------
__global__ __launch_bounds__(256) void ln_router(const float* __restrict__ in,
                                                 const float* __restrict__ g,
                                                 const float* __restrict__ b,
                                                 const float* __restrict__ wr,
                                                 unsigned short* __restrict__ outb,
                                                 int* __restrict__ cnt,
                                                 int* __restrict__ expTok,
                                                 int* __restrict__ tokE,
                                                 int* __restrict__ tokPos,
                                                 float* __restrict__ tokGate){
    int t = blockIdx.x;
    const float* row = in + (size_t)t * DM;
    int tid = threadIdx.x;
    float v0 = row[tid], v1 = row[tid + 256], v2 = row[tid + 512];
    float s  = v0 + v1 + v2;
    float ss = v0*v0 + v1*v1 + v2*v2;
    for (int off = 32; off; off >>= 1){
        s  += __shfl_down(s, off);
        ss += __shfl_down(ss, off);
    }
    __shared__ float ls[4], lss[4];
    __shared__ float wsum[4][NEXP];
    int wid = tid >> 6, lane = tid & 63;
    if (lane == 0){ ls[wid] = s; lss[wid] = ss; }
    __syncthreads();
    if (tid == 0){
        float a = ls[0] + ls[1] + ls[2] + ls[3];
        float c = lss[0] + lss[1] + lss[2] + lss[3];
        float mu = a / (float)DM;
        float var = c / (float)DM - mu * mu;
        ls[0] = mu; lss[0] = rsqrtf(var + LNEPS);
    }
    __syncthreads();
    float mu = ls[0], rs = lss[0];
    float o0 = (v0 - mu) * rs * g[tid]       + b[tid];
    float o1 = (v1 - mu) * rs * g[tid + 256] + b[tid + 256];
    float o2 = (v2 - mu) * rs * g[tid + 512] + b[tid + 512];
    unsigned short* obrow = outb + (size_t)t * DM;
    obrow[tid] = f2bf(o0); obrow[tid+256] = f2bf(o1); obrow[tid+512] = f2bf(o2);
    float p[NEXP];
    #pragma unroll
    for (int e = 0; e < NEXP; e++)
        p[e] = o0*wr[e*DM + tid] + o1*wr[e*DM + tid + 256] + o2*wr[e*DM + tid + 512];
    #pragma unroll
    for (int e = 0; e < NEXP; e++)
        for (int off = 32; off; off >>= 1) p[e] += __shfl_down(p[e], off);
    if (lane == 0){
        #pragma unroll
        for (int e = 0; e < NEXP; e++) wsum[wid][e] = p[e];
    }
    __syncthreads();
    if (tid == 0){
        float lg[NEXP];
        #pragma unroll
        for (int e = 0; e < NEXP; e++)
            lg[e] = wsum[0][e] + wsum[1][e] + wsum[2][e] + wsum[3][e];
        int i0 = 0; float m0 = lg[0];
        #pragma unroll
        for (int e = 1; e < NEXP; e++) if (lg[e] > m0){ m0 = lg[e]; i0 = e; }
        int i1 = -1; float m1 = -INFINITY;
        #pragma unroll
        for (int e = 0; e < NEXP; e++) if (e != i0 && lg[e] > m1){ m1 = lg[e]; i1 = e; }
        float mx = fmaxf(m0, m1);
        float e0 = __expf(m0 - mx), e1 = __expf(m1 - mx);
        float inv = 1.0f / (e0 + e1);
        int p0 = atomicAdd(&cnt[i0], 1);
        int p1 = atomicAdd(&cnt[i1], 1);
        expTok[i0*NTOK + p0] = t;
        expTok[i1*NTOK + p1] = t;
        tokE[t*2]   = i0; tokE[t*2+1]   = i1;
        tokPos[t*2] = p0; tokPos[t*2+1] = p1;
        tokGate[t*2]   = e0 * inv;
        tokGate[t*2+1] = e1 * inv;
    }
}

// ---------------- QKV GEMM (64x128 tile) + fused attn prep epilogue ----------------
// A = xb [2048][768], B = Wab [2304][768]; writes Qb/Kb [bh][s][64] bf16, Vt [bh][d][s] bf16
__global__ __launch_bounds__(256) void mm_qkv(const unsigned short* __restrict__ Ab,
                                              const unsigned short* __restrict__ Bb,
                                              const float* __restrict__ bias,
                                              unsigned short* __restrict__ Qb,
                                              unsigned short* __restrict__ Kb,
                                              unsigned short* __restrict__ Vt){
    __shared__ __align__(16) unsigned short As[64*32];
    __shared__ __align__(16) unsigned short Bs[128*32];
    int bm = blockIdx.y * 64, bn = blockIdx.x * 128;
    int tid = threadIdx.x, wave = tid >> 6, lane = tid & 63;
    int quad = lane >> 4, l15 = lane & 15;
    int wm = wave >> 1, wn = wave & 1;
    int arow = tid >> 2, achunk = (tid & 3) * 8;
    int lrow = lane >> 2, lchunk = (lane & 3) * 8;
    const unsigned short* aS  = Ab + (size_t)(bm + arow) * DM + achunk;
    const unsigned short* bS0 = Bb + (size_t)(bn +      wave*16 + lrow) * DM + lchunk;
    const unsigned short* bS1 = Bb + (size_t)(bn + 64 + wave*16 + lrow) * DM + lchunk;
    unsigned short* aD  = &As[(wave*16)*32];
    unsigned short* bD0 = &Bs[(     wave*16)*32];
    unsigned short* bD1 = &Bs[(64 + wave*16)*32];
    v4f acc[2][4];
    #pragma unroll
    for (int i = 0; i < 2; i++)
        #pragma unroll
        for (int j = 0; j < 4; j++) acc[i][j] = (v4f){0.f,0.f,0.f,0.f};
    for (int kt = 0; kt < DM/32; kt++){
        int kb = kt * 32;
        GLDS16(aS + kb, aD); GLDS16(bS0 + kb, bD0); GLDS16(bS1 + kb, bD1);
        __syncthreads();
        v8s a[2], bfr[4];
        #pragma unroll
        for (int i = 0; i < 2; i++) a[i] = *(const v8s*)&As[(wm*32 + i*16 + l15)*32 + quad*8];
        #pragma unroll
        for (int i = 0; i < 4; i++) bfr[i] = *(const v8s*)&Bs[(wn*64 + i*16 + l15)*32 + quad*8];
        #pragma unroll
        for (int mi = 0; mi < 2; mi++)
            #pragma unroll
            for (int ni = 0; ni < 4; ni++)
                acc[mi][ni] = __builtin_amdgcn_mfma_f32_16x16x32_bf16(a[mi], bfr[ni], acc[mi][ni], 0, 0, 0);
        __syncthreads();
    }
    int btyp = bn / DM;   // 0=Q, 1=K, 2=V (128 | 768)
    #pragma unroll
    for (int ni = 0; ni < 4; ni++){
        int n = bn + wn*64 + ni*16 + l15;
        float bb = bias[n];
        int hd = n % DM; int h = hd >> 6; int d = hd & 63;
        #pragma unroll
        for (int mi = 0; mi < 2; mi++){
            int m = bm + wm*32 + mi*16 + quad*4;
            int b = m >> 10, sd = m & 1023;
            size_t bhbase = (size_t)(b*NHEAD + h);
            if (btyp == 0){
                #pragma unroll
                for (int r = 0; r < 4; r++)
                    Qb[(bhbase*SEQ + sd + r)*HDIM + d] = f2bf((acc[mi][ni][r] + bb) * 0.125f);
            } else if (btyp == 1){
                #pragma unroll
                for (int r = 0; r < 4; r++)
                    Kb[(bhbase*SEQ + sd + r)*HDIM + d] = f2bf(acc[mi][ni][r] + bb);
            } else {
                ushort4 o;
                o.x = f2bf(acc[mi][ni][0] + bb); o.y = f2bf(acc[mi][ni][1] + bb);
                o.z = f2bf(acc[mi][ni][2] + bb); o.w = f2bf(acc[mi][ni][3] + bb);
                *(ushort4*)&Vt[(bhbase*HDIM + d)*SEQ + sd] = o;
            }
        }
    }
}

// ---------------- Flash attention: one wave per (bh, 32-query tile) ----------------
__global__ __launch_bounds__(64) void fattn(const unsigned short* __restrict__ Qb,
                                            const unsigned short* __restrict__ Kb,
                                            const unsigned short* __restrict__ Vt,
                                            unsigned short* __restrict__ ctxb){
    int bh = blockIdx.x >> 5;
    int q0 = (31 - (blockIdx.x & 31)) * 32;   // long tiles first
    int h = bh % NHEAD, b = bh / NHEAD;
    int lane = threadIdx.x;
    int quad = lane >> 4, l15 = lane & 15;

    __shared__ __align__(16) unsigned short Plds[32*32];

    const unsigned short* qp = Qb + ((size_t)bh*SEQ + q0 + l15) * HDIM + quad*8;
    v8s qa00 = *(const v8s*)qp;
    v8s qa01 = *(const v8s*)(qp + 32);
    v8s qa10 = *(const v8s*)(qp + 16*HDIM);
    v8s qa11 = *(const v8s*)(qp + 16*HDIM + 32);

    v4f o[2][4];
    #pragma unroll
    for (int i = 0; i < 2; i++)
        #pragma unroll
        for (int j = 0; j < 4; j++) o[i][j] = (v4f){0.f,0.f,0.f,0.f};
    float mrow[2][4], lrow[2][4];
    #pragma unroll
    for (int i = 0; i < 2; i++)
        #pragma unroll
        for (int r = 0; r < 4; r++){ mrow[i][r] = -1e30f; lrow[i][r] = 0.f; }

    int nch = (q0 >> 5) + 1;
    for (int ch = 0; ch < nch; ch++){
        int kt = ch * 32;
        const unsigned short* kp = Kb + ((size_t)bh*SEQ + kt + l15) * HDIM + quad*8;
        v8s k00 = *(const v8s*)kp;
        v8s k01 = *(const v8s*)(kp + 32);
        v8s k10 = *(const v8s*)(kp + 16*HDIM);
        v8s k11 = *(const v8s*)(kp + 16*HDIM + 32);
        v4f s00 = {0,0,0,0}, s01 = {0,0,0,0}, s10 = {0,0,0,0}, s11 = {0,0,0,0};
        s00 = __builtin_amdgcn_mfma_f32_16x16x32_bf16(qa00, k00, s00, 0, 0, 0);
        s00 = __builtin_amdgcn_mfma_f32_16x16x32_bf16(qa01, k01, s00, 0, 0, 0);
        s01 = __builtin_amdgcn_mfma_f32_16x16x32_bf16(qa00, k10, s01, 0, 0, 0);
        s01 = __builtin_amdgcn_mfma_f32_16x16x32_bf16(qa01, k11, s01, 0, 0, 0);
        s10 = __builtin_amdgcn_mfma_f32_16x16x32_bf16(qa10, k00, s10, 0, 0, 0);
        s10 = __builtin_amdgcn_mfma_f32_16x16x32_bf16(qa11, k01, s10, 0, 0, 0);
        s11 = __builtin_amdgcn_mfma_f32_16x16x32_bf16(qa10, k10, s11, 0, 0, 0);
        s11 = __builtin_amdgcn_mfma_f32_16x16x32_bf16(qa11, k11, s11, 0, 0, 0);

        int key0 = kt + l15, key1 = kt + 16 + l15;
        float alpha[2][4];
        #pragma unroll
        for (int mi = 0; mi < 2; mi++){
            #pragma unroll
            for (int r = 0; r < 4; r++){
                int qrow = q0 + mi*16 + quad*4 + r;
                float sv0 = mi ? s10[r] : s00[r];
                float sv1 = mi ? s11[r] : s01[r];
                float v0 = (key0 <= qrow) ? sv0 : -1e30f;
                float v1 = (key1 <= qrow) ? sv1 : -1e30f;
                float mx = fmaxf(v0, v1);
                mx = fmaxf(mx, __shfl_xor(mx, 1));
                mx = fmaxf(mx, __shfl_xor(mx, 2));
                mx = fmaxf(mx, __shfl_xor(mx, 4));
                mx = fmaxf(mx, __shfl_xor(mx, 8));
                float mn = fmaxf(mrow[mi][r], mx);
                alpha[mi][r] = __expf(mrow[mi][r] - mn);
                float p0 = __expf(v0 - mn);
                float p1 = __expf(v1 - mn);
                float ps = p0 + p1;
                ps += __shfl_xor(ps, 1);
                ps += __shfl_xor(ps, 2);
                ps += __shfl_xor(ps, 4);
                ps += __shfl_xor(ps, 8);
                lrow[mi][r] = lrow[mi][r] * alpha[mi][r] + ps;
                mrow[mi][r] = mn;
                Plds[(mi*16 + quad*4 + r)*32 + l15]      = f2bf(p0);
                Plds[(mi*16 + quad*4 + r)*32 + 16 + l15] = f2bf(p1);
            }
        }
        #pragma unroll
        for (int mi = 0; mi < 2; mi++)
            #pragma unroll
            for (int df = 0; df < 4; df++)
                #pragma unroll
                for (int r = 0; r < 4; r++)
                    o[mi][df][r] *= alpha[mi][r];
        __syncthreads();
        v8s pa0 = *(const v8s*)&Plds[l15*32 + quad*8];
        v8s pa1 = *(const v8s*)&Plds[(16 + l15)*32 + quad*8];
        const unsigned short* vp = Vt + ((size_t)bh*HDIM + l15) * SEQ + kt + quad*8;
        #pragma unroll
        for (int df = 0; df < 4; df++){
            v8s vb = *(const v8s*)(vp + df*16*SEQ);
            o[0][df] = __builtin_amdgcn_mfma_f32_16x16x32_bf16(pa0, vb, o[0][df], 0, 0, 0);
            o[1][df] = __builtin_amdgcn_mfma_f32_16x16x32_bf16(pa1, vb, o[1][df], 0, 0, 0);
        }
        __syncthreads();
    }
    #pragma unroll
    for (int mi = 0; mi < 2; mi++){
        #pragma unroll
        for (int r = 0; r < 4; r++){
            float inv = 1.0f / lrow[mi][r];
            size_t orow = (size_t)(b*SEQ + q0 + mi*16 + quad*4 + r) * DM + h*HDIM;
            #pragma unroll
            for (int df = 0; df < 4; df++)
                ctxb[orow + df*16 + l15] = f2bf(o[mi][df][r] * inv);
        }
    }
}

// ---------------- attn-proj GEMM (64x64 tile) + bias + residual -> hs fp32 ----------------
__global__ __launch_bounds__(256) void mm_attnproj(const unsigned short* __restrict__ Ab,
                                                   const unsigned short* __restrict__ Bb,
                                                   const float* __restrict__ bias,
                                                   const float* __restrict__ res,
                                                   float* __restrict__ C){
    __shared__ __align__(16) unsigned short As[64*32];
    __shared__ __align__(16) unsigned short Bs[64*32];
    int bm = blockIdx.y * 64, bn = blockIdx.x * 64;
    int tid = threadIdx.x, wave = tid >> 6, lane = tid & 63;
    int quad = lane >> 4, l15 = lane & 15;
    int wm = wave >> 1, wn = wave & 1;
    int arow = tid >> 2, achunk = (tid & 3) * 8;
    const unsigned short* aS = Ab + (size_t)(bm + arow) * DM + achunk;
    const unsigned short* bS = Bb + (size_t)(bn + arow) * DM + achunk;
    unsigned short* aD = &As[(wave*16)*32];
    unsigned short* bD = &Bs[(wave*16)*32];
    v4f acc[2][2];
    #pragma unroll
    for (int i = 0; i < 2; i++)
        #pragma unroll
        for (int j = 0; j < 2; j++) acc[i][j] = (v4f){0.f,0.f,0.f,0.f};
    for (int kt = 0; kt < DM/32; kt++){
        int kb = kt * 32;
        GLDS16(aS + kb, aD); GLDS16(bS + kb, bD);
        __syncthreads();
        v8s a[2], bfr[2];
        #pragma unroll
        for (int i = 0; i < 2; i++){
            a[i]   = *(const v8s*)&As[(wm*32 + i*16 + l15)*32 + quad*8];
            bfr[i] = *(const v8s*)&Bs[(wn*32 + i*16 + l15)*32 + quad*8];
        }
        #pragma unroll
        for (int mi = 0; mi < 2; mi++)
            #pragma unroll
            for (int ni = 0; ni < 2; ni++)
                acc[mi][ni] = __builtin_amdgcn_mfma_f32_16x16x32_bf16(a[mi], bfr[ni], acc[mi][ni], 0, 0, 0);
        __syncthreads();
    }
    #pragma unroll
    for (int ni = 0; ni < 2; ni++){
        int n = bn + wn*32 + ni*16 + l15;
        float bb = bias[n];
        #pragma unroll
        for (int mi = 0; mi < 2; mi++){
            int m = bm + wm*32 + mi*16 + quad*4;
            #pragma unroll
            for (int r = 0; r < 4; r++)
                C[(size_t)(m + r) * DM + n] = acc[mi][ni][r] + bb + res[(size_t)(m + r) * DM + n];
        }
    }
}

// ---------------- MoE fc (128x128 tile): gathered xb rows @ Wfcb[e] + bias, gelu -> H bf16 ----------------
__global__ __launch_bounds__(256) void mm_fc(const unsigned short* __restrict__ Xb,
                                             const unsigned short* __restrict__ Wb,
                                             const float* __restrict__ bfc,
                                             const int* __restrict__ expTok,
                                             const int* __restrict__ cnt,
                                             const int* __restrict__ offE,
                                             unsigned short* __restrict__ H){
    int e = blockIdx.z, tile = blockIdx.y;
    int c = cnt[e];
    int rows = c - tile * 128;
    if (rows <= 0) return;
    __shared__ __align__(16) unsigned short As[128*32];
    __shared__ __align__(16) unsigned short Bs[128*32];
    __shared__ int toks[128];
    int bn = blockIdx.x * 128;
    int tid = threadIdx.x, wave = tid >> 6, lane = tid & 63;
    if (tid < 128){
        int idx = tile * 128 + tid;
        if (idx >= c) idx = c - 1;
        toks[tid] = expTok[e * NTOK + idx];
    }
    __syncthreads();
    int quad = lane >> 4, l15 = lane & 15;
    int wm = wave >> 1, wn = wave & 1;
    int lrow = lane >> 2, lchunk = (lane & 3) * 8;
    int tok0 = toks[     wave*16 + lrow];
    int tok1 = toks[64 + wave*16 + lrow];
    const unsigned short* Be = Wb + (size_t)e * FF * DM;
    const unsigned short* aS0 = Xb + (size_t)tok0 * DM + lchunk;
    const unsigned short* aS1 = Xb + (size_t)tok1 * DM + lchunk;
    const unsigned short* bS0 = Be + (size_t)(bn +      wave*16 + lrow) * DM + lchunk;
    const unsigned short* bS1 = Be + (size_t)(bn + 64 + wave*16 + lrow) * DM + lchunk;
    unsigned short* aD0 = &As[(     wave*16)*32];
    unsigned short* aD1 = &As[(64 + wave*16)*32];
    unsigned short* bD0 = &Bs[(     wave*16)*32];
    unsigned short* bD1 = &Bs[(64 + wave*16)*32];
    v4f acc[4][4];
    #pragma unroll
    for (int i = 0; i < 4; i++)
        #pragma unroll
        for (int j = 0; j < 4; j++) acc[i][j] = (v4f){0.f,0.f,0.f,0.f};
    for (int kt = 0; kt < DM/32; kt++){
        int kb = kt * 32;
        GLDS16(aS0 + kb, aD0); GLDS16(aS1 + kb, aD1);
        GLDS16(bS0 + kb, bD0); GLDS16(bS1 + kb, bD1);
        __syncthreads();
        v8s a[4], bfr[4];
        #pragma unroll
        for (int i = 0; i < 4; i++){
            a[i]   = *(const v8s*)&As[(wm*64 + i*16 + l15)*32 + quad*8];
            bfr[i] = *(const v8s*)&Bs[(wn*64 + i*16 + l15)*32 + quad*8];
        }
        #pragma unroll
        for (int mt = 0; mt < 4; mt++)
            #pragma unroll
            for (int nt = 0; nt < 4; nt++)
                acc[mt][nt] = __builtin_amdgcn_mfma_f32_16x16x32_bf16(a[mt], bfr[nt], acc[mt][nt], 0, 0, 0);
        __syncthreads();
    }
    int slot0 = offE[e] + tile * 128;
    #pragma unroll
    for (int nt = 0; nt < 4; nt++){
        int n = bn + wn*64 + nt*16 + l15;
        float bb = bfc[(size_t)e * FF + n];
        #pragma unroll
        for (int mt = 0; mt < 4; mt++){
            int ml = wm*64 + mt*16 + quad*4;
            #pragma unroll
            for (int r = 0; r < 4; r++)
                if (ml + r < rows)
                    H[(size_t)(slot0 + ml + r) * FF + n] = f2bf(gelu_exact(acc[mt][nt][r] + bb));
        }
    }
}

// ---------------- MoE proj (64x128 tile, split-K=2): H @ Wprb[e] -> Yp[sk] fp32 ----------------
__global__ __launch_bounds__(256) void mm_proj(const unsigned short* __restrict__ H,
                                               const unsigned short* __restrict__ Wb,
                                               const int* __restrict__ cnt,
                                               const int* __restrict__ offE,
                                               float* __restrict__ Yp){
    int e = blockIdx.z, tile = blockIdx.y;
    int c = cnt[e];
    int rows = c - tile * 64;
    if (rows <= 0) return;
    int sk = blockIdx.x & 1;
    int bn = (blockIdx.x >> 1) * 128;
    __shared__ __align__(16) unsigned short As[64*32];
    __shared__ __align__(16) unsigned short Bs[128*32];
    int tid = threadIdx.x, wave = tid >> 6, lane = tid & 63;
    int quad = lane >> 4, l15 = lane & 15;
    int wm = wave >> 1, wn = wave & 1;
    int slot0 = offE[e] + tile * 64;
    int arow = tid >> 2, achunk = (tid & 3) * 8;
    int arl = arow < rows ? arow : rows - 1;
    int lrow = lane >> 2, lchunk = (lane & 3) * 8;
    const unsigned short* Be = Wb + (size_t)e * DM * FF;
    const unsigned short* aS  = H  + (size_t)(slot0 + arl) * FF + sk*1536 + achunk;
    const unsigned short* bS0 = Be + (size_t)(bn +      wave*16 + lrow) * FF + sk*1536 + lchunk;
    const unsigned short* bS1 = Be + (size_t)(bn + 64 + wave*16 + lrow) * FF + sk*1536 + lchunk;
    unsigned short* aD  = &As[(wave*16)*32];
    unsigned short* bD0 = &Bs[(     wave*16)*32];
    unsigned short* bD1 = &Bs[(64 + wave*16)*32];
    v4f acc[2][4];
    #pragma unroll
    for (int i = 0; i < 2; i++)
        #pragma unroll
        for (int j = 0; j < 4; j++) acc[i][j] = (v4f){0.f,0.f,0.f,0.f};
    for (int kt = 0; kt < 1536/32; kt++){
        int kb = kt * 32;
        GLDS16(aS + kb, aD); GLDS16(bS0 + kb, bD0); GLDS16(bS1 + kb, bD1);
        __syncthreads();
        v8s a[2], bfr[4];
        #pragma unroll
        for (int i = 0; i < 2; i++) a[i] = *(const v8s*)&As[(wm*32 + i*16 + l15)*32 + quad*8];
        #pragma unroll
        for (int i = 0; i < 4; i++) bfr[i] = *(const v8s*)&Bs[(wn*64 + i*16 + l15)*32 + quad*8];
        #pragma unroll
        for (int mi = 0; mi < 2; mi++)
            #pragma unroll
            for (int ni = 0; ni < 4; ni++)
                acc[mi][ni] = __builtin_amdgcn_mfma_f32_16x16x32_bf16(a[mi], bfr[ni], acc[mi][ni], 0, 0, 0);
        __syncthreads();
    }
    float* Yo = Yp + (size_t)sk * NSLOT * DM;
    #pragma unroll
    for (int ni = 0; ni < 4; ni++){
        int n = bn + wn*64 + ni*16 + l15;
        #pragma unroll
        for (int mi = 0; mi < 2; mi++){
            int ml = wm*32 + mi*16 + quad*4;
            #pragma unroll
            for (int r = 0; r < 4; r++)
                if (ml + r < rows)
                    Yo[(size_t)(slot0 + ml + r) * DM + n] = acc[mi][ni][r];
        }
    }
}

__global__ void offsets_kernel(const int* __restrict__ cnt, int* __restrict__ offE){
    if (threadIdx.x == 0 && blockIdx.x == 0){
        int a = 0;
        for (int e = 0; e < NEXP; e++){ offE[e] = a; a += cnt[e]; }
    }
}

// ---------------- Combine: out = hs + sum_k gate_k * (Yp0+Yp1 + b_proj[e_k]) ----------------
__global__ __launch_bounds__(256) void combine_kernel(const float* __restrict__ hs,
                                                      const float* __restrict__ Yp,
                                                      const float* __restrict__ bproj,
                                                      const int* __restrict__ tokE,
                                                      const int* __restrict__ tokPos,
                                                      const float* __restrict__ tokGate,
                                                      const int* __restrict__ offE,
                                                      float* __restrict__ out){
    int t = blockIdx.x;
    int e0 = tokE[t*2], e1 = tokE[t*2+1];
    int s0 = offE[e0] + tokPos[t*2];
    int s1 = offE[e1] + tokPos[t*2+1];
    float g0 = tokGate[t*2], g1 = tokGate[t*2+1];
    const float* y0a = Yp + (size_t)s0 * DM;
    const float* y0b = Yp + (size_t)NSLOT * DM + (size_t)s0 * DM;
    const float* y1a = Yp + (size_t)s1 * DM;
    const float* y1b = Yp + (size_t)NSLOT * DM + (size_t)s1 * DM;
    const float* b0 = bproj + (size_t)e0 * DM;
    const float* b1 = bproj + (size_t)e1 * DM;
    const float* hr = hs + (size_t)t * DM;
    float* orow = out + (size_t)t * DM;
    for (int d = threadIdx.x; d < DM; d += 256){
        orow[d] = hr[d] + g0 * (y0a[d] + y0b[d] + b0[d]) + g1 * (y1a[d] + y1b[d] + b1[d]);
    }
}

extern "C" void kernel_launch(void* const* d_in, const int* in_sizes, int n_in,
                              void* d_out, int out_size, void* d_ws, size_t ws_size,
                              hipStream_t stream){
    (void)in_sizes; (void)n_in; (void)out_size; (void)ws_size;
    const float* hidden  = (const float*)d_in[0];
    const float* ln1_g   = (const float*)d_in[1];
    const float* ln1_b   = (const float*)d_in[2];
    const float* w_attn  = (const float*)d_in[3];
    const float* b_attn  = (const float*)d_in[4];
    const float* w_aproj = (const float*)d_in[5];
    const float* b_aproj = (const float*)d_in[6];
    const float* ln2_g   = (const float*)d_in[7];
    const float* ln2_b   = (const float*)d_in[8];
    const float* w_rout  = (const float*)d_in[9];
    const float* w_fc    = (const float*)d_in[10];
    const float* b_fc    = (const float*)d_in[11];
    const float* w_proj  = (const float*)d_in[12];
    const float* b_proj  = (const float*)d_in[13];
    float* out = (float*)d_out;

    char* ws = (char*)d_ws;
    // layout (bytes):
    float*          hs   = (float*)(ws + 0);                      //  6,291,456
    unsigned short* xb   = (unsigned short*)(ws + 6291456);       //  3,145,728
    unsigned short* Qb   = (unsigned short*)(ws + 9437184);       //  3,145,728
    unsigned short* Kb   = (unsigned short*)(ws + 12582912);      //  3,145,728
    unsigned short* Vt   = (unsigned short*)(ws + 15728640);      //  3,145,728
    unsigned short* ctxb = (unsigned short*)(ws + 18874368);      //  3,145,728
    unsigned short* Wab  = (unsigned short*)(ws + 22020096);      //  3,538,944
    unsigned short* Wapb = (unsigned short*)(ws + 25559040);      //  1,179,648
    // H overlays Qb..Wapb (all dead by mm_fc) + fresh space up to 34,603,008
    unsigned short* H    = (unsigned short*)(ws + 9437184);       // 25,165,824 overlay
    unsigned short* Wfcb = (unsigned short*)(ws + 34603008);      // 37,748,736
    unsigned short* Wprb = (unsigned short*)(ws + 72351744);      // 37,748,736
    // Yp (2 split-K partials) overlays Wfcb (dead after mm_fc)
    float*          Yp   = (float*)(ws + 34603008);               // 25,165,824 overlay
    char* rt = ws + 110100480;
    int* cnt      = (int*)(rt + 0);
    int* offE     = (int*)(rt + 64);
    int* expTok   = (int*)(rt + 128);                   // 65,536
    int* tokE     = (int*)(rt + 128 + 65536);           // 16,384
    int* tokPos   = (int*)(rt + 128 + 81920);           // 16,384
    float* tokGate= (float*)(rt + 128 + 98304);         // 16,384

    hipMemsetAsync(cnt, 0, NEXP * sizeof(int), stream);

    // weight transpose+convert to bf16 [N][K]
    tconv_kernel<<<dim3(TDIM/32, DM/32, 1), 256, 0, stream>>>(w_attn, Wab, DM, TDIM);
    tconv_kernel<<<dim3(DM/32, DM/32, 1), 256, 0, stream>>>(w_aproj, Wapb, DM, DM);
    tconv_kernel<<<dim3(FF/32, DM/32, NEXP), 256, 0, stream>>>(w_fc, Wfcb, DM, FF);
    tconv_kernel<<<dim3(DM/32, FF/32, NEXP), 256, 0, stream>>>(w_proj, Wprb, FF, DM);

    ln_b<<<NTOK, 256, 0, stream>>>(hidden, ln1_g, ln1_b, xb);
    mm_qkv<<<dim3(TDIM/128, NTOK/64), 256, 0, stream>>>(xb, Wab, b_attn, Qb, Kb, Vt);
    fattn<<<NB*NHEAD*32, 64, 0, stream>>>(Qb, Kb, Vt, ctxb);
    mm_attnproj<<<dim3(DM/64, NTOK/64), 256, 0, stream>>>(ctxb, Wapb, b_aproj, hidden, hs);
    ln_router<<<NTOK, 256, 0, stream>>>(hs, ln2_g, ln2_b, w_rout, xb,
                                        cnt, expTok, tokE, tokPos, tokGate);
    offsets_kernel<<<1, 64, 0, stream>>>(cnt, offE);
    mm_fc<<<dim3(FF/128, NTOK/128, NEXP), 256, 0, stream>>>(xb, Wfcb, b_fc, expTok, cnt, offE, H);
    mm_proj<<<dim3((DM/128)*2, NTOK/64, NEXP), 256, 0, stream>>>(H, Wprb, cnt, offE, Yp);
    combine_kernel<<<NTOK, 256, 0, stream>>>(hs, Yp, b_proj, tokE, tokPos, tokGate, offE, out);
}